// Round 1
// 529.817 us; speedup vs baseline: 1.0925x; 1.0925x over previous
//
#include <hip/hip_runtime.h>
#include <math.h>

#define NN 512
#define BB 8
#define CC 64
#define TT 64
#define LL 58
#define CL (CC*LL)        // 3712
#define BCL (BB*CC*LL)    // 29696
#define SZ ((size_t)NN*BCL)   // 15,204,352 elements per state

typedef _Float16 half8 __attribute__((ext_vector_type(8)));
typedef _Float16 half4 __attribute__((ext_vector_type(4)));
typedef float f32x4 __attribute__((ext_vector_type(4)));

// ---------------- adjacency normalization ----------------
__global__ __launch_bounds__(64) void prep_adj(const float* __restrict__ adj,
                                               float* __restrict__ dinv1,
                                               float* __restrict__ dinv2){
  int v = blockIdx.x;
  int lane = threadIdx.x;
  float rs = 0.f, cs = 0.f;
  for (int w = lane; w < NN; w += 64){
    rs += adj[v*NN + w];
    cs += adj[w*NN + v];
  }
  for (int off = 32; off > 0; off >>= 1){
    rs += __shfl_down(rs, off);
    cs += __shfl_down(cs, off);
  }
  if (lane == 0){
    dinv1[v] = 1.f / sqrtf(rs + 1.f);
    dinv2[v] = 1.f / sqrtf(cs + 1.f);
  }
}

// emits M = D^-1/2(A+I)D^-1/2 - I  (f(y) = M·y since 0.5*ALPHA = 1, DT=1)
__global__ __launch_bounds__(256) void build_norm(const float* __restrict__ adj,
                                                  const float* __restrict__ dinv1,
                                                  const float* __restrict__ dinv2,
                                                  _Float16* __restrict__ An,
                                                  _Float16* __restrict__ AnT){
  int v = blockIdx.x;
  float d1v = dinv1[v], d2v = dinv2[v];
  for (int w = threadIdx.x; w < NN; w += 256){
    float diag = (v == w) ? 1.f : 0.f;
    An[v*NN + w]  = (_Float16)(d1v * (adj[v*NN + w] + diag) * dinv1[w] - diag);
    AnT[v*NN + w] = (_Float16)(d2v * (adj[w*NN + v] + diag) * dinv2[w] - diag);
  }
}

// ---------------- U prep: fold RK/concat coefficients into combine weights ----
__global__ __launch_bounds__(256) void u_prep(const float* __restrict__ W1,
                                              const float* __restrict__ W2,
                                              _Float16* __restrict__ U1,
                                              _Float16* __restrict__ U2){
  const float coef[5][5] = {
    {1.f, 1.f, 1.f, 1.f, 1.f},
    {0.f, 1.f/3.f, 2.f/3.f, 1.f, 1.f},
    {0.f, 0.f, 1.f/3.f, 1.f/3.f, 0.5f},
    {0.f, 0.f, 0.f, 1.f/3.f, 1.f/6.f},
    {0.f, 0.f, 0.f, 0.f, 1.f/24.f}};
  int idx = blockIdx.x*256 + threadIdx.x;   // grid 80 -> 20480
  int o = idx / 320, rem = idx - o*320;
  int d = rem >> 6, c = rem & 63;
  float a1 = 0.f, a2 = 0.f;
  #pragma unroll
  for (int s = 0; s < 5; ++s){
    float cf = coef[d][s];
    a1 += cf * W1[o*320 + s*64 + c];
    a2 += cf * W2[o*320 + s*64 + c];
  }
  U1[idx] = (_Float16)a1;
  U2[idx] = (_Float16)a2;
}

// ---------------- inception weight prep ----------------
__global__ __launch_bounds__(448) void wfg_prep(
    const float* __restrict__ w10, const float* __restrict__ w11,
    const float* __restrict__ w12, const float* __restrict__ w13,
    const float* __restrict__ w20, const float* __restrict__ w21,
    const float* __restrict__ w22, const float* __restrict__ w23,
    const float* __restrict__ b10, const float* __restrict__ b11,
    const float* __restrict__ b12, const float* __restrict__ b13,
    const float* __restrict__ b20, const float* __restrict__ b21,
    const float* __restrict__ b22, const float* __restrict__ b23,
    _Float16* __restrict__ WfG, float* __restrict__ biasFG){
  int r = blockIdx.x;         // 0..127
  int t = threadIdx.x;        // 0..447
  int qp = t >> 6, ic = t & 63;
  int gate = r >> 6;
  int j = (r >> 4) & 3;
  int oc = r & 15;
  const int kjs[4] = {2, 3, 6, 7};
  int kj = kjs[j];
  const float* wsel = gate ? ((j==0)?w20:(j==1)?w21:(j==2)?w22:w23)
                           : ((j==0)?w10:(j==1)?w11:(j==2)?w12:w13);
  int off = 7 - kj;
  float val = (qp >= off) ? wsel[(oc*64 + ic)*kj + (qp - off)] : 0.f;
  WfG[(size_t)r*448 + t] = (_Float16)val;
  if (t == 0){
    const float* bsel = gate ? ((j==0)?b20:(j==1)?b21:(j==2)?b22:b23)
                             : ((j==0)?b10:(j==1)?b11:(j==2)?b12:b13);
    biasFG[r] = bsel[oc];
  }
}

// ---------------- x transpose: x[b][ic][n][t] f32 -> xTg[b][t][n][ic] f16 ----------------
__global__ __launch_bounds__(256) void xt_prep(const float* __restrict__ x,
                                               _Float16* __restrict__ xTg){
  __shared__ float T[64][65];
  int n = blockIdx.x;   // 512
  int b = blockIdx.y;   // 8
  int tid = threadIdx.x;
  #pragma unroll
  for (int r = 0; r < 4; ++r){
    int f = tid + r*256;       // 0..1023
    int ic = f >> 4, t4 = f & 15;
    float4 v = *(const float4*)&x[(((size_t)(b*64 + ic))*512 + n)*64 + t4*4];
    T[ic][t4*4+0] = v.x; T[ic][t4*4+1] = v.y;
    T[ic][t4*4+2] = v.z; T[ic][t4*4+3] = v.w;
  }
  __syncthreads();
  #pragma unroll
  for (int r = 0; r < 2; ++r){
    int f = tid + r*256;       // 0..511
    int t = f >> 3, ch = f & 7;
    half8 hv;
    #pragma unroll
    for (int q2 = 0; q2 < 8; ++q2) hv[q2] = (_Float16)T[ch*8 + q2][t];
    *(half8*)&xTg[(((size_t)(b*64 + t))*512 + n)*64 + ch*8] = hv;
  }
}

// ---------------- inception via MFMA ----------------
__global__ __launch_bounds__(256, 3) void inception_mfma(
    const _Float16* __restrict__ xTg,   // [b][t][n][ic]
    const _Float16* __restrict__ WfG,   // [128][448]
    const float* __restrict__ biasFG,   // [128]
    _Float16* __restrict__ S_h){
  __shared__ _Float16 X[13*32*64];      // indexed in 8-half chunks
  int nt = blockIdx.x;   // 0..15
  int lt = blockIdx.y;   // 0..8
  int b  = blockIdx.z;   // 0..7
  int n0 = nt*32, l0 = lt*7;
  int tid = threadIdx.x;

  int sch = tid & 7, sn = (tid >> 3) & 31;
  #pragma unroll
  for (int r = 0; r < 13; ++r){
    int t = l0 + r;
    half8 v = {};
    if (t < 64)
      v = *(const half8*)&xTg[(((size_t)(b*64 + t))*512 + n0 + sn)*64 + sch*8];
    *(half8*)&X[(size_t)(r*256 + sn*8 + (sch ^ (sn & 7)))*8] = v;
  }

  int w = tid >> 6, lane = tid & 63;
  int m = lane & 15, kg = lane >> 4;

  half8 wF[14], wG[14];
  const _Float16* wb = WfG + (size_t)(w*16 + m)*448 + kg*8;
  #pragma unroll
  for (int s = 0; s < 14; ++s){
    wF[s] = *(const half8*)(wb + s*32);
    wG[s] = *(const half8*)(wb + (size_t)64*448 + s*32);
  }
  f32x4 bF = *(const f32x4*)&biasFG[w*16 + kg*4];
  f32x4 bG = *(const f32x4*)&biasFG[64 + w*16 + kg*4];

  __syncthreads();

  for (int ll = 0; ll < 7; ++ll){
    f32x4 aF0 = {}, aF1 = {}, aG0 = {}, aG1 = {};
    #pragma unroll
    for (int s = 0; s < 14; ++s){
      int t = ll + (s >> 1);
      int c0 = (s & 1)*4 + kg;
      half8 b0 = *(half8*)&X[(size_t)(t*256 + m*8        + (c0 ^ (m & 7)))*8];
      half8 b1 = *(half8*)&X[(size_t)(t*256 + (16+m)*8   + (c0 ^ (m & 7)))*8];
      aF0 = __builtin_amdgcn_mfma_f32_16x16x32_f16(wF[s], b0, aF0, 0, 0, 0);
      aG0 = __builtin_amdgcn_mfma_f32_16x16x32_f16(wG[s], b0, aG0, 0, 0, 0);
      aF1 = __builtin_amdgcn_mfma_f32_16x16x32_f16(wF[s], b1, aF1, 0, 0, 0);
      aG1 = __builtin_amdgcn_mfma_f32_16x16x32_f16(wG[s], b1, aG1, 0, 0, 0);
    }
    int l = l0 + ll;
    if (l < LL){
      #pragma unroll
      for (int rr = 0; rr < 4; ++rr){
        int c = w*16 + kg*4 + rr;
        float F0 = aF0[rr] + bF[rr];
        float G0 = aG0[rr] + bG[rr];
        float F1 = aF1[rr] + bF[rr];
        float G1 = aG1[rr] + bG[rr];
        float h0 = (2.f*__builtin_amdgcn_rcpf(1.f + __expf(-2.f*F0)) - 1.f)
                 * __builtin_amdgcn_rcpf(1.f + __expf(-G0));
        float h1 = (2.f*__builtin_amdgcn_rcpf(1.f + __expf(-2.f*F1)) - 1.f)
                 * __builtin_amdgcn_rcpf(1.f + __expf(-G1));
        size_t base = ((size_t)(b*64 + c)*LL + l)*NN + n0;
        S_h[base + m]      = (_Float16)h0;
        S_h[base + 16 + m] = (_Float16)h1;
      }
    }
  }
}

// ---------------- dual Krylov GEMM v2: 256x256 tile, 8 waves, BK=64 ---------
// O[m][v] = sum_k B[m][k] * A[v][k].
// global_load_lds(16B) staging, double-buffered (128KB LDS), counted vmcnt(8)
// (never drained to 0 in steady state), raw s_barrier, setprio around MFMA.
// XOR chunk swizzle done on the GLOBAL source address (LDS dest stays linear,
// as global_load_lds requires); reads apply the same involution:
//   LDS[r][c] holds global chunk (c ^ (r&7))  (chunks = 16B units of the
//   64-half K-slice). ds_read then lands 8 lanes per bank-quad with distinct
//   rows = exactly the 1024B/128B minimum -> conflict-free.
__device__ __forceinline__ void gll16(const _Float16* g, _Float16* l){
  __builtin_amdgcn_global_load_lds(
      (const __attribute__((address_space(1))) unsigned int*)g,
      (__attribute__((address_space(3))) unsigned int*)l, 16, 0, 0);
}

__global__ __launch_bounds__(512, 2) void gemm_z2(
    const _Float16* __restrict__ A0, const _Float16* __restrict__ B0,
    _Float16* __restrict__ O0,
    const _Float16* __restrict__ A1, const _Float16* __restrict__ B1,
    _Float16* __restrict__ O1){
  const _Float16* __restrict__ A = blockIdx.z ? A1 : A0;
  const _Float16* __restrict__ B = blockIdx.z ? B1 : B0;
  _Float16* __restrict__ O = blockIdx.z ? O1 : O0;

  // [A buf0 | B buf0 | A buf1 | B buf1], each 256 rows x 64 halfs = 16384
  __shared__ _Float16 L[65536];   // 128 KB

  const int m0 = blockIdx.x * 256;
  const int v0 = blockIdx.y * 256;
  const int tid = threadIdx.x;
  const int ww = tid >> 6;          // wave 0..7
  const int lane = tid & 63;
  const int lr = lane & 15;
  const int kg = lane >> 4;
  const int wv = ww >> 2;           // v half   (0..1) -> 128 rows
  const int wm = ww & 3;            // m quarter(0..3) ->  64 rows

  // ---- staging geometry: per instr, 64 lanes fill 8 rows x 8 chunks linear.
  // lane l -> row +(l>>3), LDS chunk (l&7); global chunk = (l&7)^((l>>3)&7).
  const int srow = lane >> 3;
  const int schk = (lane & 7) ^ srow;
  const _Float16* gA = A + (size_t)(v0 + ww*32 + srow)*NN + schk*8;
  const _Float16* gB = B + (size_t)(m0 + ww*32 + srow)*NN + schk*8;
  _Float16* ldsA = L + ww*2048;          // rows ww*32.. ; +s*512 per 8 rows
  _Float16* ldsB = ldsA + 16384;

  #define STAGE(buf, kt)                                                  \
    {                                                                     \
      const _Float16* ga_ = gA + (kt)*64;                                 \
      const _Float16* gb_ = gB + (kt)*64;                                 \
      _Float16* la_ = ldsA + (buf)*32768;                                 \
      _Float16* lb_ = ldsB + (buf)*32768;                                 \
      _Pragma("unroll")                                                   \
      for (int s_ = 0; s_ < 4; ++s_){                                     \
        gll16(ga_ + (size_t)s_*8*NN, la_ + s_*512);                       \
        gll16(gb_ + (size_t)s_*8*NN, lb_ + s_*512);                       \
      }                                                                   \
    }

  f32x4 acc[8][4] = {};

  // prologue: tiles 0,1 in flight; wait only for tile 0 (counted vmcnt)
  STAGE(0, 0)
  STAGE(1, 1)
  asm volatile("s_waitcnt vmcnt(8)" ::: "memory");
  asm volatile("s_barrier" ::: "memory");

  const int axor = lr & 7;
  const int aBase = (wv*128 + lr)*64;        // + i*1024 per 16 rows
  const int bBase = (wm*64 + lr)*64;         // + j*1024 per 16 rows
  const int c0 = ((kg    ) ^ axor)*8;        // kk=0 chunk offset (halfs)
  const int c1 = ((kg + 4) ^ axor)*8;        // kk=1

  for (int kt = 0; kt < 8; ++kt){
    const _Float16* la = L + (kt & 1)*32768;
    const _Float16* lb = la + 16384;
    half8 af[8], bf[4];

    // ---- kk = 0
    #pragma unroll
    for (int i = 0; i < 8; ++i) af[i] = *(const half8*)&la[aBase + i*1024 + c0];
    #pragma unroll
    for (int j = 0; j < 4; ++j) bf[j] = *(const half8*)&lb[bBase + j*1024 + c0];
    __builtin_amdgcn_s_setprio(1);
    #pragma unroll
    for (int i = 0; i < 8; ++i)
      #pragma unroll
      for (int j = 0; j < 4; ++j)
        acc[i][j] = __builtin_amdgcn_mfma_f32_16x16x32_f16(af[i], bf[j], acc[i][j], 0, 0, 0);
    __builtin_amdgcn_s_setprio(0);

    // ---- kk = 1 reads, then free this buffer for restaging
    #pragma unroll
    for (int i = 0; i < 8; ++i) af[i] = *(const half8*)&la[aBase + i*1024 + c1];
    #pragma unroll
    for (int j = 0; j < 4; ++j) bf[j] = *(const half8*)&lb[bBase + j*1024 + c1];
    asm volatile("s_waitcnt lgkmcnt(0)" ::: "memory");   // own reads landed
    asm volatile("s_barrier" ::: "memory");              // ALL waves done reading cur

    if (kt < 6) STAGE(kt & 1, kt + 2)                    // overwrite cur with kt+2

    __builtin_amdgcn_s_setprio(1);
    #pragma unroll
    for (int i = 0; i < 8; ++i)
      #pragma unroll
      for (int j = 0; j < 4; ++j)
        acc[i][j] = __builtin_amdgcn_mfma_f32_16x16x32_f16(af[i], bf[j], acc[i][j], 0, 0, 0);
    __builtin_amdgcn_s_setprio(0);

    // counted wait: ensure tile kt+1 landed; tile kt+2's 8 loads stay in flight
    if (kt < 6){
      asm volatile("s_waitcnt vmcnt(8)" ::: "memory");
      asm volatile("s_barrier" ::: "memory");
    } else if (kt == 6){
      asm volatile("s_waitcnt vmcnt(0)" ::: "memory");
      asm volatile("s_barrier" ::: "memory");
    }
  }
  #undef STAGE

  // epilogue: D layout col=lane&15 (m), row=(lane>>4)*4+rr (v)
  #pragma unroll
  for (int i = 0; i < 8; ++i){
    int vrow = v0 + wv*128 + i*16 + kg*4;
    #pragma unroll
    for (int j = 0; j < 4; ++j){
      int mcol = m0 + wm*64 + j*16 + lr;
      half4 oq;
      #pragma unroll
      for (int rr = 0; rr < 4; ++rr) oq[rr] = (_Float16)acc[i][j][rr];
      *(half4*)&O[(size_t)mcol*NN + vrow] = oq;
    }
  }
}

// ---------------- 1x1 mix via MFMA over Krylov basis ----------------
template<int PASS>
__global__ __launch_bounds__(256) void combine_mfma(
    const _Float16* __restrict__ Sh, const _Float16* __restrict__ S2,
    const _Float16* __restrict__ S3, const _Float16* __restrict__ S4,
    const _Float16* __restrict__ Sf,
    const _Float16* __restrict__ Wc,   // U_p [64][320] f16
    const float* __restrict__ bias,    // [64]
    _Float16* __restrict__ tmp){
  __shared__ _Float16 Xsh[64*258];
  __shared__ _Float16 Wsh[64*72];
  __shared__ float Bsh[64];
  int v0 = blockIdx.x * 256;
  int l  = blockIdx.y;
  int b  = blockIdx.z;
  int tid = threadIdx.x;
  int w = tid >> 6, lane = tid & 63;
  int lr = lane & 15, kg = lane >> 4;

  if (tid < 64) Bsh[tid] = bias[tid];

  const _Float16* Sarr[5] = {Sh, S2, S3, S4, Sf};
  f32x4 acc[4][4] = {};   // [vt][jj]

  for (int kt = 0; kt < 5; ++kt){
    const _Float16* S = Sarr[kt];
    __syncthreads();
    #pragma unroll
    for (int r = 0; r < 8; ++r){
      int f = tid + r*256;        // 0..2047
      int c = f >> 5, ch = f & 31;
      half8 xv = *(const half8*)&S[((size_t)(b*64 + c)*58 + l)*512 + v0 + ch*8];
      *(half8*)&Xsh[c*258 + ch*8] = xv;
    }
    #pragma unroll
    for (int r = 0; r < 2; ++r){
      int f = tid + r*256;        // 0..511
      int o = f >> 3, ch = f & 7;
      *(half8*)&Wsh[o*72 + ch*8] = *(const half8*)&Wc[(size_t)o*320 + kt*64 + ch*8];
    }
    __syncthreads();

    #pragma unroll
    for (int ks = 0; ks < 2; ++ks){
      int k0 = ks*32;
      half8 aW[4];
      #pragma unroll
      for (int jj = 0; jj < 4; ++jj)
        aW[jj] = *(half8*)&Wsh[(jj*16 + lr)*72 + k0 + kg*8];
      #pragma unroll
      for (int vt = 0; vt < 4; ++vt){
        half8 bX;
        #pragma unroll
        for (int j = 0; j < 8; ++j)
          bX[j] = Xsh[(k0 + kg*8 + j)*258 + w*64 + vt*16 + lr];
        #pragma unroll
        for (int jj = 0; jj < 4; ++jj)
          acc[vt][jj] = __builtin_amdgcn_mfma_f32_16x16x32_f16(aW[jj], bX, acc[vt][jj], 0, 0, 0);
      }
    }
  }

  size_t rowbase = ((size_t)b*58 + l)*64;
  #pragma unroll
  for (int jj = 0; jj < 4; ++jj){
    #pragma unroll
    for (int rr = 0; rr < 4; ++rr){
      int o = jj*16 + kg*4 + rr;
      float bv = Bsh[o];
      size_t obase = (rowbase + o)*512 + v0 + w*64 + lr;
      #pragma unroll
      for (int vt = 0; vt < 4; ++vt){
        float val = acc[vt][jj][rr] + bv;
        size_t addr = obase + vt*16;
        if (PASS == 0) tmp[addr] = (_Float16)val;
        else           tmp[addr] = (_Float16)((float)tmp[addr] + val);
      }
    }
  }
}

// ---------------- untranspose tmp[(b,l)][o][v] -> out[b][o][v][6+l], zero pad ----------------
__global__ __launch_bounds__(256) void untranspose(const _Float16* __restrict__ tmp,
                                                   float* __restrict__ out){
  __shared__ float T[58][65];
  int o = blockIdx.x;          // 64
  int b = blockIdx.y;          // 8
  int v0 = blockIdx.z * 64;    // 8
  int t = threadIdx.x;
  for (int idx = t; idx < 58*64; idx += 256){
    int lr = idx >> 6, vv = idx & 63;
    T[lr][vv] = (float)tmp[((size_t)(b*58 + lr)*64 + o)*NN + v0 + vv];
  }
  __syncthreads();
  #pragma unroll
  for (int i = 0; i < 16; ++i){
    int c = t + i*256;           // 0..4095
    int vv = c >> 6, tt = c & 63;
    float val = (tt < 6) ? 0.f : T[tt - 6][vv];
    out[((size_t)(b*64 + o)*NN + v0 + vv)*TT + tt] = val;
  }
}

// ---------------- launch ----------------
extern "C" void kernel_launch(void* const* d_in, const int* in_sizes, int n_in,
                              void* d_out, int out_size, void* d_ws, size_t ws_size,
                              hipStream_t stream){
  const float* x   = (const float*)d_in[0];
  const float* adj = (const float*)d_in[1];
  const float* w1[4] = {(const float*)d_in[2],  (const float*)d_in[4],
                        (const float*)d_in[6],  (const float*)d_in[8]};
  const float* b1[4] = {(const float*)d_in[3],  (const float*)d_in[5],
                        (const float*)d_in[7],  (const float*)d_in[9]};
  const float* w2[4] = {(const float*)d_in[10], (const float*)d_in[12],
                        (const float*)d_in[14], (const float*)d_in[16]};
  const float* b2[4] = {(const float*)d_in[11], (const float*)d_in[13],
                        (const float*)d_in[15], (const float*)d_in[17]};
  const float* m1w = (const float*)d_in[18];
  const float* m1b = (const float*)d_in[19];
  const float* m2w = (const float*)d_in[20];
  const float* m2b = (const float*)d_in[21];

  // workspace layout (bytes) — total ~185 MB
  char* wsb = (char*)d_ws;
  float* dinv1 = (float*)(wsb);
  float* dinv2 = (float*)(wsb + 2048);
  _Float16* U1  = (_Float16*)(wsb + 4096);             // 40 KB
  _Float16* U2  = (_Float16*)(wsb + 4096 + 40960);     // 40 KB
  _Float16* Mn  = (_Float16*)(wsb + 167936);           // M = An - I
  _Float16* MnT = (_Float16*)(wsb + 167936 + 524288);
  size_t sbytes = SZ * 2;
  char* sbase = wsb + 1216512;
  _Float16* S_h = (_Float16*)(sbase);                  // z0 = h
  _Float16* S2  = (_Float16*)(sbase + sbytes);         // z1
  _Float16* S3  = (_Float16*)(sbase + 2*sbytes);       // z2
  _Float16* S4  = (_Float16*)(sbase + 3*sbytes);       // z3
  _Float16* S5  = (_Float16*)(sbase + 4*sbytes);       // z4
  _Float16* tmp = (_Float16*)(sbase + 5*sbytes);
  _Float16* xTg = S2;   // dead before first gemm writes S2
  _Float16* WfG = (_Float16*)(sbase + 6*sbytes);        // 114688 B
  float* biasFG = (float*)(sbase + 6*sbytes + 114688);  // 512 B
  _Float16* M2  = (_Float16*)(sbase + 6*sbytes + 131072);           // 512 KB
  _Float16* MT2 = (_Float16*)(sbase + 6*sbytes + 131072 + 524288);  // 512 KB
  float* out = (float*)d_out;

  prep_adj<<<NN, 64, 0, stream>>>(adj, dinv1, dinv2);
  build_norm<<<NN, 256, 0, stream>>>(adj, dinv1, dinv2, Mn, MnT);
  // M2 = Mn^2 row-major = gemm(A=MnT,B=Mn); MT2 = MnT^2 row-major = gemm(A=Mn,B=MnT)
  gemm_z2<<<dim3(NN/256, NN/256, 2), 512, 0, stream>>>(MnT, Mn, M2, Mn, MnT, MT2);
  u_prep<<<80, 256, 0, stream>>>(m1w, m2w, U1, U2);
  wfg_prep<<<128, 448, 0, stream>>>(
      w1[0],w1[1],w1[2],w1[3], w2[0],w2[1],w2[2],w2[3],
      b1[0],b1[1],b1[2],b1[3], b2[0],b2[1],b2[2],b2[3], WfG, biasFG);
  xt_prep<<<dim3(NN, BB), 256, 0, stream>>>(x, xTg);
  inception_mfma<<<dim3(16, 9, 8), 256, 0, stream>>>(xTg, WfG, biasFG, S_h);

  dim3 gz(BCL/256, NN/256, 2);   // 116 x 2 x 2
  dim3 gc(2, LL, BB);
  for (int pass = 0; pass < 2; ++pass){
    const _Float16* Mp  = pass ? MnT : Mn;
    const _Float16* Mp2 = pass ? MT2 : M2;
    // z1 = Mp·h, z2 = Mp²·h   (independent)
    gemm_z2<<<gz, 512, 0, stream>>>(Mp, S_h, S2, Mp2, S_h, S3);
    // z3 = Mp²·z1, z4 = Mp²·z2 (independent)
    gemm_z2<<<gz, 512, 0, stream>>>(Mp2, S2, S4, Mp2, S3, S5);
    if (pass == 0)
      combine_mfma<0><<<gc, 256, 0, stream>>>(S_h, S2, S3, S4, S5, U1, m1b, tmp);
    else
      combine_mfma<1><<<gc, 256, 0, stream>>>(S_h, S2, S3, S4, S5, U2, m2b, tmp);
  }
  untranspose<<<dim3(64, 8, 8), 256, 0, stream>>>(tmp, out);
}

// Round 2
// 491.728 us; speedup vs baseline: 1.1772x; 1.0775x over previous
//
#include <hip/hip_runtime.h>
#include <math.h>

#define NN 512
#define BB 8
#define CC 64
#define TT 64
#define LL 58
#define CL (CC*LL)        // 3712
#define BCL (BB*CC*LL)    // 29696
#define SZ ((size_t)NN*BCL)   // 15,204,352 elements per state

typedef _Float16 half8 __attribute__((ext_vector_type(8)));
typedef _Float16 half4 __attribute__((ext_vector_type(4)));
typedef float f32x4 __attribute__((ext_vector_type(4)));

// ---------------- adjacency normalization ----------------
__global__ __launch_bounds__(64) void prep_adj(const float* __restrict__ adj,
                                               float* __restrict__ dinv1,
                                               float* __restrict__ dinv2){
  int v = blockIdx.x;
  int lane = threadIdx.x;
  float rs = 0.f, cs = 0.f;
  for (int w = lane; w < NN; w += 64){
    rs += adj[v*NN + w];
    cs += adj[w*NN + v];
  }
  for (int off = 32; off > 0; off >>= 1){
    rs += __shfl_down(rs, off);
    cs += __shfl_down(cs, off);
  }
  if (lane == 0){
    dinv1[v] = 1.f / sqrtf(rs + 1.f);
    dinv2[v] = 1.f / sqrtf(cs + 1.f);
  }
}

// emits M = D^-1/2(A+I)D^-1/2 - I  (f(y) = M·y since 0.5*ALPHA = 1, DT=1)
__global__ __launch_bounds__(256) void build_norm(const float* __restrict__ adj,
                                                  const float* __restrict__ dinv1,
                                                  const float* __restrict__ dinv2,
                                                  _Float16* __restrict__ An,
                                                  _Float16* __restrict__ AnT){
  int v = blockIdx.x;
  float d1v = dinv1[v], d2v = dinv2[v];
  for (int w = threadIdx.x; w < NN; w += 256){
    float diag = (v == w) ? 1.f : 0.f;
    An[v*NN + w]  = (_Float16)(d1v * (adj[v*NN + w] + diag) * dinv1[w] - diag);
    AnT[v*NN + w] = (_Float16)(d2v * (adj[w*NN + v] + diag) * dinv2[w] - diag);
  }
}

// ---------------- U prep: fold RK/concat coefficients into combine weights ----
__global__ __launch_bounds__(256) void u_prep(const float* __restrict__ W1,
                                              const float* __restrict__ W2,
                                              _Float16* __restrict__ U1,
                                              _Float16* __restrict__ U2){
  const float coef[5][5] = {
    {1.f, 1.f, 1.f, 1.f, 1.f},
    {0.f, 1.f/3.f, 2.f/3.f, 1.f, 1.f},
    {0.f, 0.f, 1.f/3.f, 1.f/3.f, 0.5f},
    {0.f, 0.f, 0.f, 1.f/3.f, 1.f/6.f},
    {0.f, 0.f, 0.f, 0.f, 1.f/24.f}};
  int idx = blockIdx.x*256 + threadIdx.x;   // grid 80 -> 20480
  int o = idx / 320, rem = idx - o*320;
  int d = rem >> 6, c = rem & 63;
  float a1 = 0.f, a2 = 0.f;
  #pragma unroll
  for (int s = 0; s < 5; ++s){
    float cf = coef[d][s];
    a1 += cf * W1[o*320 + s*64 + c];
    a2 += cf * W2[o*320 + s*64 + c];
  }
  U1[idx] = (_Float16)a1;
  U2[idx] = (_Float16)a2;
}

// ---------------- inception weight prep ----------------
__global__ __launch_bounds__(448) void wfg_prep(
    const float* __restrict__ w10, const float* __restrict__ w11,
    const float* __restrict__ w12, const float* __restrict__ w13,
    const float* __restrict__ w20, const float* __restrict__ w21,
    const float* __restrict__ w22, const float* __restrict__ w23,
    const float* __restrict__ b10, const float* __restrict__ b11,
    const float* __restrict__ b12, const float* __restrict__ b13,
    const float* __restrict__ b20, const float* __restrict__ b21,
    const float* __restrict__ b22, const float* __restrict__ b23,
    _Float16* __restrict__ WfG, float* __restrict__ biasFG){
  int r = blockIdx.x;         // 0..127
  int t = threadIdx.x;        // 0..447
  int qp = t >> 6, ic = t & 63;
  int gate = r >> 6;
  int j = (r >> 4) & 3;
  int oc = r & 15;
  const int kjs[4] = {2, 3, 6, 7};
  int kj = kjs[j];
  const float* wsel = gate ? ((j==0)?w20:(j==1)?w21:(j==2)?w22:w23)
                           : ((j==0)?w10:(j==1)?w11:(j==2)?w12:w13);
  int off = 7 - kj;
  float val = (qp >= off) ? wsel[(oc*64 + ic)*kj + (qp - off)] : 0.f;
  WfG[(size_t)r*448 + t] = (_Float16)val;
  if (t == 0){
    const float* bsel = gate ? ((j==0)?b20:(j==1)?b21:(j==2)?b22:b23)
                             : ((j==0)?b10:(j==1)?b11:(j==2)?b12:b13);
    biasFG[r] = bsel[oc];
  }
}

// ---------------- x transpose: x[b][ic][n][t] f32 -> xTg[b][t][n][ic] f16 ----------------
__global__ __launch_bounds__(256) void xt_prep(const float* __restrict__ x,
                                               _Float16* __restrict__ xTg){
  __shared__ float T[64][65];
  int n = blockIdx.x;   // 512
  int b = blockIdx.y;   // 8
  int tid = threadIdx.x;
  #pragma unroll
  for (int r = 0; r < 4; ++r){
    int f = tid + r*256;       // 0..1023
    int ic = f >> 4, t4 = f & 15;
    float4 v = *(const float4*)&x[(((size_t)(b*64 + ic))*512 + n)*64 + t4*4];
    T[ic][t4*4+0] = v.x; T[ic][t4*4+1] = v.y;
    T[ic][t4*4+2] = v.z; T[ic][t4*4+3] = v.w;
  }
  __syncthreads();
  #pragma unroll
  for (int r = 0; r < 2; ++r){
    int f = tid + r*256;       // 0..511
    int t = f >> 3, ch = f & 7;
    half8 hv;
    #pragma unroll
    for (int q2 = 0; q2 < 8; ++q2) hv[q2] = (_Float16)T[ch*8 + q2][t];
    *(half8*)&xTg[(((size_t)(b*64 + t))*512 + n)*64 + ch*8] = hv;
  }
}

// ---------------- inception via MFMA ----------------
__global__ __launch_bounds__(256, 3) void inception_mfma(
    const _Float16* __restrict__ xTg,   // [b][t][n][ic]
    const _Float16* __restrict__ WfG,   // [128][448]
    const float* __restrict__ biasFG,   // [128]
    _Float16* __restrict__ S_h){
  __shared__ _Float16 X[13*32*64];      // indexed in 8-half chunks
  int nt = blockIdx.x;   // 0..15
  int lt = blockIdx.y;   // 0..8
  int b  = blockIdx.z;   // 0..7
  int n0 = nt*32, l0 = lt*7;
  int tid = threadIdx.x;

  int sch = tid & 7, sn = (tid >> 3) & 31;
  #pragma unroll
  for (int r = 0; r < 13; ++r){
    int t = l0 + r;
    half8 v = {};
    if (t < 64)
      v = *(const half8*)&xTg[(((size_t)(b*64 + t))*512 + n0 + sn)*64 + sch*8];
    *(half8*)&X[(size_t)(r*256 + sn*8 + (sch ^ (sn & 7)))*8] = v;
  }

  int w = tid >> 6, lane = tid & 63;
  int m = lane & 15, kg = lane >> 4;

  half8 wF[14], wG[14];
  const _Float16* wb = WfG + (size_t)(w*16 + m)*448 + kg*8;
  #pragma unroll
  for (int s = 0; s < 14; ++s){
    wF[s] = *(const half8*)(wb + s*32);
    wG[s] = *(const half8*)(wb + (size_t)64*448 + s*32);
  }
  f32x4 bF = *(const f32x4*)&biasFG[w*16 + kg*4];
  f32x4 bG = *(const f32x4*)&biasFG[64 + w*16 + kg*4];

  __syncthreads();

  for (int ll = 0; ll < 7; ++ll){
    f32x4 aF0 = {}, aF1 = {}, aG0 = {}, aG1 = {};
    #pragma unroll
    for (int s = 0; s < 14; ++s){
      int t = ll + (s >> 1);
      int c0 = (s & 1)*4 + kg;
      half8 b0 = *(half8*)&X[(size_t)(t*256 + m*8        + (c0 ^ (m & 7)))*8];
      half8 b1 = *(half8*)&X[(size_t)(t*256 + (16+m)*8   + (c0 ^ (m & 7)))*8];
      aF0 = __builtin_amdgcn_mfma_f32_16x16x32_f16(wF[s], b0, aF0, 0, 0, 0);
      aG0 = __builtin_amdgcn_mfma_f32_16x16x32_f16(wG[s], b0, aG0, 0, 0, 0);
      aF1 = __builtin_amdgcn_mfma_f32_16x16x32_f16(wF[s], b1, aF1, 0, 0, 0);
      aG1 = __builtin_amdgcn_mfma_f32_16x16x32_f16(wG[s], b1, aG1, 0, 0, 0);
    }
    int l = l0 + ll;
    if (l < LL){
      #pragma unroll
      for (int rr = 0; rr < 4; ++rr){
        int c = w*16 + kg*4 + rr;
        float F0 = aF0[rr] + bF[rr];
        float G0 = aG0[rr] + bG[rr];
        float F1 = aF1[rr] + bF[rr];
        float G1 = aG1[rr] + bG[rr];
        float h0 = (2.f*__builtin_amdgcn_rcpf(1.f + __expf(-2.f*F0)) - 1.f)
                 * __builtin_amdgcn_rcpf(1.f + __expf(-G0));
        float h1 = (2.f*__builtin_amdgcn_rcpf(1.f + __expf(-2.f*F1)) - 1.f)
                 * __builtin_amdgcn_rcpf(1.f + __expf(-G1));
        size_t base = ((size_t)(b*64 + c)*LL + l)*NN + n0;
        S_h[base + m]      = (_Float16)h0;
        S_h[base + 16 + m] = (_Float16)h1;
      }
    }
  }
}

// ---------------- dual Krylov GEMM v3: 256x256, BK=64, true 8-phase --------
// O[m][v] = sum_k B[m][k] * A[v][k].
// 4 phases per K-tile (16 MFMA each); per phase: {ds-read frags; 1 half-tile
// (kk-half) global_load_lds stage; barrier; MFMA; [vmcnt(8) @P1/P3]; barrier}.
// kk-half-granular staging gives 4-6 phases of HBM lead; vmcnt never drains
// to 0 until the tail. LDS: [buf][A/B][kk][256 rows][4x16B chunks] = 128KB.
// Chunk swizzle c' = c ^ (row&3) applied on the GLOBAL source (linear LDS
// dest, as global_load_lds requires) and on the ds_read side -> conflict-free.
// Epilogue: per-wave 16KB LDS transpose -> 256B-contiguous coalesced stores.
__device__ __forceinline__ void gll16(const _Float16* g, _Float16* l){
  __builtin_amdgcn_global_load_lds(
      (const __attribute__((address_space(1))) unsigned int*)g,
      (__attribute__((address_space(3))) unsigned int*)l, 16, 0, 0);
}
#define BAR() asm volatile("s_barrier" ::: "memory")

__global__ __launch_bounds__(512, 2) void gemm_z2(
    int nx,
    const _Float16* __restrict__ A0, const _Float16* __restrict__ B0,
    _Float16* __restrict__ O0,
    const _Float16* __restrict__ A1, const _Float16* __restrict__ B1,
    _Float16* __restrict__ O1){
  __shared__ _Float16 L[65536];   // 128 KB

  // bijective XCD-chunked remap (gridDim.x % 8 == 0); y-pairs (shared B rows)
  // adjacent within an XCD chunk -> second B read is an L2 hit.
  int bid = blockIdx.x;
  int q8 = gridDim.x >> 3;
  int virt = (bid & 7)*q8 + (bid >> 3);
  int y = virt & 1;
  int pair = virt >> 1;
  int x = pair % nx;
  int z = pair / nx;

  const _Float16* __restrict__ A = z ? A1 : A0;
  const _Float16* __restrict__ B = z ? B1 : B0;
  _Float16* __restrict__ O = z ? O1 : O0;

  const int m0 = x * 256;
  const int v0 = y * 256;
  const int tid = threadIdx.x;
  const int ww = tid >> 6;
  const int lane = tid & 63;
  const int lr = lane & 15;
  const int kg = lane >> 4;
  const int wv = ww >> 2;           // v half   (128 rows)
  const int wm = ww & 3;            // m quarter (64 rows)

  // ---- staging: per gll16, 64 lanes fill 16 rows x 4 chunks(16B) linear.
  // lane l -> row l>>2, LDS chunk l&3; global chunk g = (l&3)^((l>>2)&3).
  const int srow = lane >> 2;
  const int gch  = (lane & 3) ^ (srow & 3);
  const _Float16* gAb = A + (size_t)(v0 + ww*32 + srow)*NN + gch*8;
  const _Float16* gBb = B + (size_t)(m0 + ww*32 + srow)*NN + gch*8;

  // LDS byte layout: buf*65536 + (B?32768:0) + kk*16384 + row*64 + chunk*16
  #define STAGE_A(tt, kk)                                                   \
    { char* l_ = (char*)L + (size_t)((tt)&1)*65536 + (size_t)(kk)*16384     \
                 + ww*2048;                                                 \
      const _Float16* g_ = gAb + (tt)*64 + (kk)*32;                         \
      gll16(g_,         (_Float16*)l_);                                     \
      gll16(g_ + 16*NN, (_Float16*)(l_ + 1024)); }
  #define STAGE_B(tt, kk)                                                   \
    { char* l_ = (char*)L + (size_t)((tt)&1)*65536 + 32768                  \
                 + (size_t)(kk)*16384 + ww*2048;                            \
      const _Float16* g_ = gBb + (tt)*64 + (kk)*32;                         \
      gll16(g_,         (_Float16*)l_);                                     \
      gll16(g_ + 16*NN, (_Float16*)(l_ + 1024)); }

  // read-side swizzled frag offsets (bytes within a [256][4chunk] region)
  const int csw = (kg ^ (lr & 3)) * 16;
  const int aR = (wv*128 + lr)*64 + csw;          // + i*1024
  const int bR = 32768 + (wm*64 + lr)*64 + csw;   // + j*1024

  half8 af[4], bf[4];
  f32x4 acc[8][4] = {};

  #define LOADS_A(buf, kk, ih)                                              \
    _Pragma("unroll")                                                       \
    for (int q_ = 0; q_ < 4; ++q_)                                          \
      af[q_] = *(const half8*)((char*)L + (buf)*65536 + (kk)*16384          \
                               + aR + ((ih)*4 + q_)*1024);
  #define LOADS_B(buf, kk)                                                  \
    _Pragma("unroll")                                                       \
    for (int q_ = 0; q_ < 4; ++q_)                                          \
      bf[q_] = *(const half8*)((char*)L + (buf)*65536 + (kk)*16384          \
                               + bR + q_*1024);
  #define MFMA16(ih)                                                        \
    __builtin_amdgcn_s_setprio(1);                                          \
    _Pragma("unroll")                                                       \
    for (int i_ = 0; i_ < 4; ++i_)                                          \
      _Pragma("unroll")                                                     \
      for (int j_ = 0; j_ < 4; ++j_)                                        \
        acc[(ih)*4 + i_][j_] = __builtin_amdgcn_mfma_f32_16x16x32_f16(      \
            af[i_], bf[j_], acc[(ih)*4 + i_][j_], 0, 0, 0);                 \
    __builtin_amdgcn_s_setprio(0);

  // prologue: t0.kk0, t0.kk1, t1.kk0 (12 loads); wait first 4 -> vmcnt(8)
  STAGE_A(0,0) STAGE_B(0,0)
  STAGE_A(0,1) STAGE_B(0,1)
  STAGE_A(1,0) STAGE_B(1,0)
  asm volatile("s_waitcnt vmcnt(8)" ::: "memory");
  BAR();

  #pragma unroll
  for (int kt = 0; kt < 8; ++kt){
    const int buf = kt & 1;
    // ---- P0: kk0, i 0..3 (+ bf kk0); stage A(t+1).kk1
    LOADS_A(buf, 0, 0); LOADS_B(buf, 0);
    if (kt + 1 < 8) STAGE_A(kt+1, 1)
    BAR();
    MFMA16(0);
    BAR();
    // ---- P1: kk0, i 4..7; stage B(t+1).kk1; wait t.kk1 landed
    LOADS_A(buf, 0, 1);
    if (kt + 1 < 8) STAGE_B(kt+1, 1)
    BAR();
    MFMA16(1);
    if (kt < 7) { asm volatile("s_waitcnt vmcnt(8)" ::: "memory"); }
    else        { asm volatile("s_waitcnt vmcnt(0)" ::: "memory"); }
    BAR();
    // ---- P2: kk1, i 0..3 (+ bf kk1); stage A(t+2).kk0
    LOADS_A(buf, 1, 0); LOADS_B(buf, 1);
    if (kt + 2 < 8) STAGE_A(kt+2, 0)
    BAR();
    MFMA16(0);
    BAR();
    // ---- P3: kk1, i 4..7; stage B(t+2).kk0; wait (t+1).kk0 landed
    LOADS_A(buf, 1, 1);
    if (kt + 2 < 8) STAGE_B(kt+2, 0)
    BAR();
    MFMA16(1);
    if (kt < 6)      { asm volatile("s_waitcnt vmcnt(8)" ::: "memory"); }
    else if (kt == 6){ asm volatile("s_waitcnt vmcnt(4)" ::: "memory"); }
    BAR();
  }
  #undef STAGE_A
  #undef STAGE_B
  #undef LOADS_A
  #undef LOADS_B
  #undef MFMA16

  // ---- epilogue: per-wave 16KB LDS transpose -> coalesced 256B row stores.
  // local tile [m'=64][v'=128] halfs, row=256B; 8B-chunk swizzle ^(row&7)*4.
  char* Lw = (char*)L + ww*16384;
  #pragma unroll
  for (int j = 0; j < 4; ++j){
    int row = j*16 + lr;
    #pragma unroll
    for (int i = 0; i < 8; ++i){
      int c = (i*4 + kg) ^ ((lr & 7)*4);
      half4 oq;
      #pragma unroll
      for (int rr = 0; rr < 4; ++rr) oq[rr] = (_Float16)acc[i][j][rr];
      *(half4*)(Lw + row*256 + c*8) = oq;
    }
  }
  #pragma unroll
  for (int s = 0; s < 16; ++s){
    int row = s*4 + kg;
    int cc = (2*lr) ^ ((row & 7)*4);
    half8 hv = *(const half8*)(Lw + row*256 + cc*8);
    *(half8*)&O[(size_t)(m0 + wm*64 + row)*NN + v0 + wv*128 + lr*8] = hv;
  }
}

// ---------------- 1x1 mix via MFMA over Krylov basis ----------------
template<int PASS>
__global__ __launch_bounds__(256) void combine_mfma(
    const _Float16* __restrict__ Sh, const _Float16* __restrict__ S2,
    const _Float16* __restrict__ S3, const _Float16* __restrict__ S4,
    const _Float16* __restrict__ Sf,
    const _Float16* __restrict__ Wc,   // U_p [64][320] f16
    const float* __restrict__ bias,    // [64]
    _Float16* __restrict__ tmp){
  __shared__ _Float16 Xsh[64*258];
  __shared__ _Float16 Wsh[64*72];
  __shared__ float Bsh[64];
  int v0 = blockIdx.x * 256;
  int l  = blockIdx.y;
  int b  = blockIdx.z;
  int tid = threadIdx.x;
  int w = tid >> 6, lane = tid & 63;
  int lr = lane & 15, kg = lane >> 4;

  if (tid < 64) Bsh[tid] = bias[tid];

  const _Float16* Sarr[5] = {Sh, S2, S3, S4, Sf};
  f32x4 acc[4][4] = {};   // [vt][jj]

  for (int kt = 0; kt < 5; ++kt){
    const _Float16* S = Sarr[kt];
    __syncthreads();
    #pragma unroll
    for (int r = 0; r < 8; ++r){
      int f = tid + r*256;        // 0..2047
      int c = f >> 5, ch = f & 31;
      half8 xv = *(const half8*)&S[((size_t)(b*64 + c)*58 + l)*512 + v0 + ch*8];
      *(half8*)&Xsh[c*258 + ch*8] = xv;
    }
    #pragma unroll
    for (int r = 0; r < 2; ++r){
      int f = tid + r*256;        // 0..511
      int o = f >> 3, ch = f & 7;
      *(half8*)&Wsh[o*72 + ch*8] = *(const half8*)&Wc[(size_t)o*320 + kt*64 + ch*8];
    }
    __syncthreads();

    #pragma unroll
    for (int ks = 0; ks < 2; ++ks){
      int k0 = ks*32;
      half8 aW[4];
      #pragma unroll
      for (int jj = 0; jj < 4; ++jj)
        aW[jj] = *(half8*)&Wsh[(jj*16 + lr)*72 + k0 + kg*8];
      #pragma unroll
      for (int vt = 0; vt < 4; ++vt){
        half8 bX;
        #pragma unroll
        for (int j = 0; j < 8; ++j)
          bX[j] = Xsh[(k0 + kg*8 + j)*258 + w*64 + vt*16 + lr];
        #pragma unroll
        for (int jj = 0; jj < 4; ++jj)
          acc[vt][jj] = __builtin_amdgcn_mfma_f32_16x16x32_f16(aW[jj], bX, acc[vt][jj], 0, 0, 0);
      }
    }
  }

  size_t rowbase = ((size_t)b*58 + l)*64;
  #pragma unroll
  for (int jj = 0; jj < 4; ++jj){
    #pragma unroll
    for (int rr = 0; rr < 4; ++rr){
      int o = jj*16 + kg*4 + rr;
      float bv = Bsh[o];
      size_t obase = (rowbase + o)*512 + v0 + w*64 + lr;
      #pragma unroll
      for (int vt = 0; vt < 4; ++vt){
        float val = acc[vt][jj][rr] + bv;
        size_t addr = obase + vt*16;
        if (PASS == 0) tmp[addr] = (_Float16)val;
        else           tmp[addr] = (_Float16)((float)tmp[addr] + val);
      }
    }
  }
}

// ---------------- untranspose tmp[(b,l)][o][v] -> out[b][o][v][6+l], zero pad ----------------
__global__ __launch_bounds__(256) void untranspose(const _Float16* __restrict__ tmp,
                                                   float* __restrict__ out){
  __shared__ float T[58][65];
  int o = blockIdx.x;          // 64
  int b = blockIdx.y;          // 8
  int v0 = blockIdx.z * 64;    // 8
  int t = threadIdx.x;
  for (int idx = t; idx < 58*64; idx += 256){
    int lr = idx >> 6, vv = idx & 63;
    T[lr][vv] = (float)tmp[((size_t)(b*58 + lr)*64 + o)*NN + v0 + vv];
  }
  __syncthreads();
  #pragma unroll
  for (int i = 0; i < 16; ++i){
    int c = t + i*256;           // 0..4095
    int vv = c >> 6, tt = c & 63;
    float val = (tt < 6) ? 0.f : T[tt - 6][vv];
    out[((size_t)(b*64 + o)*NN + v0 + vv)*TT + tt] = val;
  }
}

// ---------------- launch ----------------
extern "C" void kernel_launch(void* const* d_in, const int* in_sizes, int n_in,
                              void* d_out, int out_size, void* d_ws, size_t ws_size,
                              hipStream_t stream){
  const float* x   = (const float*)d_in[0];
  const float* adj = (const float*)d_in[1];
  const float* w1[4] = {(const float*)d_in[2],  (const float*)d_in[4],
                        (const float*)d_in[6],  (const float*)d_in[8]};
  const float* b1[4] = {(const float*)d_in[3],  (const float*)d_in[5],
                        (const float*)d_in[7],  (const float*)d_in[9]};
  const float* w2[4] = {(const float*)d_in[10], (const float*)d_in[12],
                        (const float*)d_in[14], (const float*)d_in[16]};
  const float* b2[4] = {(const float*)d_in[11], (const float*)d_in[13],
                        (const float*)d_in[15], (const float*)d_in[17]};
  const float* m1w = (const float*)d_in[18];
  const float* m1b = (const float*)d_in[19];
  const float* m2w = (const float*)d_in[20];
  const float* m2b = (const float*)d_in[21];

  // workspace layout (bytes) — total ~185 MB
  char* wsb = (char*)d_ws;
  float* dinv1 = (float*)(wsb);
  float* dinv2 = (float*)(wsb + 2048);
  _Float16* U1  = (_Float16*)(wsb + 4096);             // 40 KB
  _Float16* U2  = (_Float16*)(wsb + 4096 + 40960);     // 40 KB
  _Float16* Mn  = (_Float16*)(wsb + 167936);           // M = An - I
  _Float16* MnT = (_Float16*)(wsb + 167936 + 524288);
  size_t sbytes = SZ * 2;
  char* sbase = wsb + 1216512;
  _Float16* S_h = (_Float16*)(sbase);                  // z0 = h
  _Float16* S2  = (_Float16*)(sbase + sbytes);         // z1
  _Float16* S3  = (_Float16*)(sbase + 2*sbytes);       // z2
  _Float16* S4  = (_Float16*)(sbase + 3*sbytes);       // z3
  _Float16* S5  = (_Float16*)(sbase + 4*sbytes);       // z4
  _Float16* tmp = (_Float16*)(sbase + 5*sbytes);
  _Float16* xTg = S2;   // dead before first gemm writes S2
  _Float16* WfG = (_Float16*)(sbase + 6*sbytes);        // 114688 B
  float* biasFG = (float*)(sbase + 6*sbytes + 114688);  // 512 B
  _Float16* M2  = (_Float16*)(sbase + 6*sbytes + 131072);           // 512 KB
  _Float16* MT2 = (_Float16*)(sbase + 6*sbytes + 131072 + 524288);  // 512 KB
  float* out = (float*)d_out;

  prep_adj<<<NN, 64, 0, stream>>>(adj, dinv1, dinv2);
  build_norm<<<NN, 256, 0, stream>>>(adj, dinv1, dinv2, Mn, MnT);
  // M2 = Mn^2 row-major = gemm(A=MnT,B=Mn); MT2 = MnT^2 row-major = gemm(A=Mn,B=MnT)
  gemm_z2<<<8, 512, 0, stream>>>(2, MnT, Mn, M2, Mn, MnT, MT2);
  u_prep<<<80, 256, 0, stream>>>(m1w, m2w, U1, U2);
  wfg_prep<<<128, 448, 0, stream>>>(
      w1[0],w1[1],w1[2],w1[3], w2[0],w2[1],w2[2],w2[3],
      b1[0],b1[1],b1[2],b1[3], b2[0],b2[1],b2[2],b2[3], WfG, biasFG);
  xt_prep<<<dim3(NN, BB), 256, 0, stream>>>(x, xTg);
  inception_mfma<<<dim3(16, 9, 8), 256, 0, stream>>>(xTg, WfG, biasFG, S_h);

  dim3 gc(2, LL, BB);
  for (int pass = 0; pass < 2; ++pass){
    const _Float16* Mp  = pass ? MnT : Mn;
    const _Float16* Mp2 = pass ? MT2 : M2;
    // z1 = Mp·h, z2 = Mp²·h   (independent)
    gemm_z2<<<464, 512, 0, stream>>>(116, Mp, S_h, S2, Mp2, S_h, S3);
    // z3 = Mp²·z1, z4 = Mp²·z2 (independent)
    gemm_z2<<<464, 512, 0, stream>>>(116, Mp2, S2, S4, Mp2, S3, S5);
    if (pass == 0)
      combine_mfma<0><<<gc, 256, 0, stream>>>(S_h, S2, S3, S4, S5, U1, m1b, tmp);
    else
      combine_mfma<1><<<gc, 256, 0, stream>>>(S_h, S2, S3, S4, S5, U2, m2b, tmp);
  }
  untranspose<<<dim3(64, 8, 8), 256, 0, stream>>>(tmp, out);
}

// Round 3
// 471.650 us; speedup vs baseline: 1.2273x; 1.0426x over previous
//
#include <hip/hip_runtime.h>
#include <math.h>

#define NN 512
#define BB 8
#define CC 64
#define TT 64
#define LL 58
#define CL (CC*LL)        // 3712
#define BCL (BB*CC*LL)    // 29696
#define SZ ((size_t)NN*BCL)   // 15,204,352 elements per state

typedef _Float16 half8 __attribute__((ext_vector_type(8)));
typedef _Float16 half4 __attribute__((ext_vector_type(4)));
typedef float f32x4 __attribute__((ext_vector_type(4)));

// ---------------- adjacency normalization ----------------
__global__ __launch_bounds__(64) void prep_adj(const float* __restrict__ adj,
                                               float* __restrict__ dinv1,
                                               float* __restrict__ dinv2){
  int v = blockIdx.x;
  int lane = threadIdx.x;
  float rs = 0.f, cs = 0.f;
  for (int w = lane; w < NN; w += 64){
    rs += adj[v*NN + w];
    cs += adj[w*NN + v];
  }
  for (int off = 32; off > 0; off >>= 1){
    rs += __shfl_down(rs, off);
    cs += __shfl_down(cs, off);
  }
  if (lane == 0){
    dinv1[v] = 1.f / sqrtf(rs + 1.f);
    dinv2[v] = 1.f / sqrtf(cs + 1.f);
  }
}

// emits M = D^-1/2(A+I)D^-1/2 - I  (f(y) = M·y since 0.5*ALPHA = 1, DT=1)
__global__ __launch_bounds__(256) void build_norm(const float* __restrict__ adj,
                                                  const float* __restrict__ dinv1,
                                                  const float* __restrict__ dinv2,
                                                  _Float16* __restrict__ An,
                                                  _Float16* __restrict__ AnT){
  int v = blockIdx.x;
  float d1v = dinv1[v], d2v = dinv2[v];
  for (int w = threadIdx.x; w < NN; w += 256){
    float diag = (v == w) ? 1.f : 0.f;
    An[v*NN + w]  = (_Float16)(d1v * (adj[v*NN + w] + diag) * dinv1[w] - diag);
    AnT[v*NN + w] = (_Float16)(d2v * (adj[w*NN + v] + diag) * dinv2[w] - diag);
  }
}

// ---------------- U prep: fold RK/concat coefficients into combine weights ----
__global__ __launch_bounds__(256) void u_prep(const float* __restrict__ W1,
                                              const float* __restrict__ W2,
                                              _Float16* __restrict__ U1,
                                              _Float16* __restrict__ U2){
  const float coef[5][5] = {
    {1.f, 1.f, 1.f, 1.f, 1.f},
    {0.f, 1.f/3.f, 2.f/3.f, 1.f, 1.f},
    {0.f, 0.f, 1.f/3.f, 1.f/3.f, 0.5f},
    {0.f, 0.f, 0.f, 1.f/3.f, 1.f/6.f},
    {0.f, 0.f, 0.f, 0.f, 1.f/24.f}};
  int idx = blockIdx.x*256 + threadIdx.x;   // grid 80 -> 20480
  int o = idx / 320, rem = idx - o*320;
  int d = rem >> 6, c = rem & 63;
  float a1 = 0.f, a2 = 0.f;
  #pragma unroll
  for (int s = 0; s < 5; ++s){
    float cf = coef[d][s];
    a1 += cf * W1[o*320 + s*64 + c];
    a2 += cf * W2[o*320 + s*64 + c];
  }
  U1[idx] = (_Float16)a1;
  U2[idx] = (_Float16)a2;
}

// ---------------- inception weight prep ----------------
__global__ __launch_bounds__(448) void wfg_prep(
    const float* __restrict__ w10, const float* __restrict__ w11,
    const float* __restrict__ w12, const float* __restrict__ w13,
    const float* __restrict__ w20, const float* __restrict__ w21,
    const float* __restrict__ w22, const float* __restrict__ w23,
    const float* __restrict__ b10, const float* __restrict__ b11,
    const float* __restrict__ b12, const float* __restrict__ b13,
    const float* __restrict__ b20, const float* __restrict__ b21,
    const float* __restrict__ b22, const float* __restrict__ b23,
    _Float16* __restrict__ WfG, float* __restrict__ biasFG){
  int r = blockIdx.x;         // 0..127
  int t = threadIdx.x;        // 0..447
  int qp = t >> 6, ic = t & 63;
  int gate = r >> 6;
  int j = (r >> 4) & 3;
  int oc = r & 15;
  const int kjs[4] = {2, 3, 6, 7};
  int kj = kjs[j];
  const float* wsel = gate ? ((j==0)?w20:(j==1)?w21:(j==2)?w22:w23)
                           : ((j==0)?w10:(j==1)?w11:(j==2)?w12:w13);
  int off = 7 - kj;
  float val = (qp >= off) ? wsel[(oc*64 + ic)*kj + (qp - off)] : 0.f;
  WfG[(size_t)r*448 + t] = (_Float16)val;
  if (t == 0){
    const float* bsel = gate ? ((j==0)?b20:(j==1)?b21:(j==2)?b22:b23)
                             : ((j==0)?b10:(j==1)?b11:(j==2)?b12:b13);
    biasFG[r] = bsel[oc];
  }
}

// ---------------- x transpose: x[b][ic][n][t] f32 -> xTg[b][t][n][ic] f16 ----------------
__global__ __launch_bounds__(256) void xt_prep(const float* __restrict__ x,
                                               _Float16* __restrict__ xTg){
  __shared__ float T[64][65];
  int n = blockIdx.x;   // 512
  int b = blockIdx.y;   // 8
  int tid = threadIdx.x;
  #pragma unroll
  for (int r = 0; r < 4; ++r){
    int f = tid + r*256;       // 0..1023
    int ic = f >> 4, t4 = f & 15;
    float4 v = *(const float4*)&x[(((size_t)(b*64 + ic))*512 + n)*64 + t4*4];
    T[ic][t4*4+0] = v.x; T[ic][t4*4+1] = v.y;
    T[ic][t4*4+2] = v.z; T[ic][t4*4+3] = v.w;
  }
  __syncthreads();
  #pragma unroll
  for (int r = 0; r < 2; ++r){
    int f = tid + r*256;       // 0..511
    int t = f >> 3, ch = f & 7;
    half8 hv;
    #pragma unroll
    for (int q2 = 0; q2 < 8; ++q2) hv[q2] = (_Float16)T[ch*8 + q2][t];
    *(half8*)&xTg[(((size_t)(b*64 + t))*512 + n)*64 + ch*8] = hv;
  }
}

// ---------------- inception via MFMA ----------------
__global__ __launch_bounds__(256, 3) void inception_mfma(
    const _Float16* __restrict__ xTg,   // [b][t][n][ic]
    const _Float16* __restrict__ WfG,   // [128][448]
    const float* __restrict__ biasFG,   // [128]
    _Float16* __restrict__ S_h){
  __shared__ _Float16 X[13*32*64];      // indexed in 8-half chunks
  int nt = blockIdx.x;   // 0..15
  int lt = blockIdx.y;   // 0..8
  int b  = blockIdx.z;   // 0..7
  int n0 = nt*32, l0 = lt*7;
  int tid = threadIdx.x;

  int sch = tid & 7, sn = (tid >> 3) & 31;
  #pragma unroll
  for (int r = 0; r < 13; ++r){
    int t = l0 + r;
    half8 v = {};
    if (t < 64)
      v = *(const half8*)&xTg[(((size_t)(b*64 + t))*512 + n0 + sn)*64 + sch*8];
    *(half8*)&X[(size_t)(r*256 + sn*8 + (sch ^ (sn & 7)))*8] = v;
  }

  int w = tid >> 6, lane = tid & 63;
  int m = lane & 15, kg = lane >> 4;

  half8 wF[14], wG[14];
  const _Float16* wb = WfG + (size_t)(w*16 + m)*448 + kg*8;
  #pragma unroll
  for (int s = 0; s < 14; ++s){
    wF[s] = *(const half8*)(wb + s*32);
    wG[s] = *(const half8*)(wb + (size_t)64*448 + s*32);
  }
  f32x4 bF = *(const f32x4*)&biasFG[w*16 + kg*4];
  f32x4 bG = *(const f32x4*)&biasFG[64 + w*16 + kg*4];

  __syncthreads();

  for (int ll = 0; ll < 7; ++ll){
    f32x4 aF0 = {}, aF1 = {}, aG0 = {}, aG1 = {};
    #pragma unroll
    for (int s = 0; s < 14; ++s){
      int t = ll + (s >> 1);
      int c0 = (s & 1)*4 + kg;
      half8 b0 = *(half8*)&X[(size_t)(t*256 + m*8        + (c0 ^ (m & 7)))*8];
      half8 b1 = *(half8*)&X[(size_t)(t*256 + (16+m)*8   + (c0 ^ (m & 7)))*8];
      aF0 = __builtin_amdgcn_mfma_f32_16x16x32_f16(wF[s], b0, aF0, 0, 0, 0);
      aG0 = __builtin_amdgcn_mfma_f32_16x16x32_f16(wG[s], b0, aG0, 0, 0, 0);
      aF1 = __builtin_amdgcn_mfma_f32_16x16x32_f16(wF[s], b1, aF1, 0, 0, 0);
      aG1 = __builtin_amdgcn_mfma_f32_16x16x32_f16(wG[s], b1, aG1, 0, 0, 0);
    }
    int l = l0 + ll;
    if (l < LL){
      #pragma unroll
      for (int rr = 0; rr < 4; ++rr){
        int c = w*16 + kg*4 + rr;
        float F0 = aF0[rr] + bF[rr];
        float G0 = aG0[rr] + bG[rr];
        float F1 = aF1[rr] + bF[rr];
        float G1 = aG1[rr] + bG[rr];
        float h0 = (2.f*__builtin_amdgcn_rcpf(1.f + __expf(-2.f*F0)) - 1.f)
                 * __builtin_amdgcn_rcpf(1.f + __expf(-G0));
        float h1 = (2.f*__builtin_amdgcn_rcpf(1.f + __expf(-2.f*F1)) - 1.f)
                 * __builtin_amdgcn_rcpf(1.f + __expf(-G1));
        size_t base = ((size_t)(b*64 + c)*LL + l)*NN + n0;
        S_h[base + m]      = (_Float16)h0;
        S_h[base + 16 + m] = (_Float16)h1;
      }
    }
  }
}

// ---------------- dual Krylov GEMM v3: 256x256, BK=64, true 8-phase --------
// (unchanged from round 2 — dropped out of top-5)
__device__ __forceinline__ void gll16(const _Float16* g, _Float16* l){
  __builtin_amdgcn_global_load_lds(
      (const __attribute__((address_space(1))) unsigned int*)g,
      (__attribute__((address_space(3))) unsigned int*)l, 16, 0, 0);
}
#define BAR() asm volatile("s_barrier" ::: "memory")

__global__ __launch_bounds__(512, 2) void gemm_z2(
    int nx,
    const _Float16* __restrict__ A0, const _Float16* __restrict__ B0,
    _Float16* __restrict__ O0,
    const _Float16* __restrict__ A1, const _Float16* __restrict__ B1,
    _Float16* __restrict__ O1){
  __shared__ _Float16 L[65536];   // 128 KB

  // bijective XCD-chunked remap (gridDim.x % 8 == 0); y-pairs (shared B rows)
  // adjacent within an XCD chunk -> second B read is an L2 hit.
  int bid = blockIdx.x;
  int q8 = gridDim.x >> 3;
  int virt = (bid & 7)*q8 + (bid >> 3);
  int y = virt & 1;
  int pair = virt >> 1;
  int x = pair % nx;
  int z = pair / nx;

  const _Float16* __restrict__ A = z ? A1 : A0;
  const _Float16* __restrict__ B = z ? B1 : B0;
  _Float16* __restrict__ O = z ? O1 : O0;

  const int m0 = x * 256;
  const int v0 = y * 256;
  const int tid = threadIdx.x;
  const int ww = tid >> 6;
  const int lane = tid & 63;
  const int lr = lane & 15;
  const int kg = lane >> 4;
  const int wv = ww >> 2;           // v half   (128 rows)
  const int wm = ww & 3;            // m quarter (64 rows)

  // ---- staging: per gll16, 64 lanes fill 16 rows x 4 chunks(16B) linear.
  // lane l -> row l>>2, LDS chunk l&3; global chunk g = (l&3)^((l>>2)&3).
  const int srow = lane >> 2;
  const int gch  = (lane & 3) ^ (srow & 3);
  const _Float16* gAb = A + (size_t)(v0 + ww*32 + srow)*NN + gch*8;
  const _Float16* gBb = B + (size_t)(m0 + ww*32 + srow)*NN + gch*8;

  // LDS byte layout: buf*65536 + (B?32768:0) + kk*16384 + row*64 + chunk*16
  #define STAGE_A(tt, kk)                                                   \
    { char* l_ = (char*)L + (size_t)((tt)&1)*65536 + (size_t)(kk)*16384     \
                 + ww*2048;                                                 \
      const _Float16* g_ = gAb + (tt)*64 + (kk)*32;                         \
      gll16(g_,         (_Float16*)l_);                                     \
      gll16(g_ + 16*NN, (_Float16*)(l_ + 1024)); }
  #define STAGE_B(tt, kk)                                                   \
    { char* l_ = (char*)L + (size_t)((tt)&1)*65536 + 32768                  \
                 + (size_t)(kk)*16384 + ww*2048;                            \
      const _Float16* g_ = gBb + (tt)*64 + (kk)*32;                         \
      gll16(g_,         (_Float16*)l_);                                     \
      gll16(g_ + 16*NN, (_Float16*)(l_ + 1024)); }

  // read-side swizzled frag offsets (bytes within a [256][4chunk] region)
  const int csw = (kg ^ (lr & 3)) * 16;
  const int aR = (wv*128 + lr)*64 + csw;          // + i*1024
  const int bR = 32768 + (wm*64 + lr)*64 + csw;   // + j*1024

  half8 af[4], bf[4];
  f32x4 acc[8][4] = {};

  #define LOADS_A(buf, kk, ih)                                              \
    _Pragma("unroll")                                                       \
    for (int q_ = 0; q_ < 4; ++q_)                                          \
      af[q_] = *(const half8*)((char*)L + (buf)*65536 + (kk)*16384          \
                               + aR + ((ih)*4 + q_)*1024);
  #define LOADS_B(buf, kk)                                                  \
    _Pragma("unroll")                                                       \
    for (int q_ = 0; q_ < 4; ++q_)                                          \
      bf[q_] = *(const half8*)((char*)L + (buf)*65536 + (kk)*16384          \
                               + bR + q_*1024);
  #define MFMA16(ih)                                                        \
    __builtin_amdgcn_s_setprio(1);                                          \
    _Pragma("unroll")                                                       \
    for (int i_ = 0; i_ < 4; ++i_)                                          \
      _Pragma("unroll")                                                     \
      for (int j_ = 0; j_ < 4; ++j_)                                        \
        acc[(ih)*4 + i_][j_] = __builtin_amdgcn_mfma_f32_16x16x32_f16(      \
            af[i_], bf[j_], acc[(ih)*4 + i_][j_], 0, 0, 0);                 \
    __builtin_amdgcn_s_setprio(0);

  // prologue: t0.kk0, t0.kk1, t1.kk0 (12 loads); wait first 4 -> vmcnt(8)
  STAGE_A(0,0) STAGE_B(0,0)
  STAGE_A(0,1) STAGE_B(0,1)
  STAGE_A(1,0) STAGE_B(1,0)
  asm volatile("s_waitcnt vmcnt(8)" ::: "memory");
  BAR();

  #pragma unroll
  for (int kt = 0; kt < 8; ++kt){
    const int buf = kt & 1;
    // ---- P0: kk0, i 0..3 (+ bf kk0); stage A(t+1).kk1
    LOADS_A(buf, 0, 0); LOADS_B(buf, 0);
    if (kt + 1 < 8) STAGE_A(kt+1, 1)
    BAR();
    MFMA16(0);
    BAR();
    // ---- P1: kk0, i 4..7; stage B(t+1).kk1; wait t.kk1 landed
    LOADS_A(buf, 0, 1);
    if (kt + 1 < 8) STAGE_B(kt+1, 1)
    BAR();
    MFMA16(1);
    if (kt < 7) { asm volatile("s_waitcnt vmcnt(8)" ::: "memory"); }
    else        { asm volatile("s_waitcnt vmcnt(0)" ::: "memory"); }
    BAR();
    // ---- P2: kk1, i 0..3 (+ bf kk1); stage A(t+2).kk0
    LOADS_A(buf, 1, 0); LOADS_B(buf, 1);
    if (kt + 2 < 8) STAGE_A(kt+2, 0)
    BAR();
    MFMA16(0);
    BAR();
    // ---- P3: kk1, i 4..7; stage B(t+2).kk0; wait (t+1).kk0 landed
    LOADS_A(buf, 1, 1);
    if (kt + 2 < 8) STAGE_B(kt+2, 0)
    BAR();
    MFMA16(1);
    if (kt < 6)      { asm volatile("s_waitcnt vmcnt(8)" ::: "memory"); }
    else if (kt == 6){ asm volatile("s_waitcnt vmcnt(4)" ::: "memory"); }
    BAR();
  }
  #undef STAGE_A
  #undef STAGE_B
  #undef LOADS_A
  #undef LOADS_B
  #undef MFMA16

  // ---- epilogue: per-wave 16KB LDS transpose -> coalesced 256B row stores.
  // local tile [m'=64][v'=128] halfs, row=256B; 8B-chunk swizzle ^(row&7)*4.
  char* Lw = (char*)L + ww*16384;
  #pragma unroll
  for (int j = 0; j < 4; ++j){
    int row = j*16 + lr;
    #pragma unroll
    for (int i = 0; i < 8; ++i){
      int c = (i*4 + kg) ^ ((lr & 7)*4);
      half4 oq;
      #pragma unroll
      for (int rr = 0; rr < 4; ++rr) oq[rr] = (_Float16)acc[i][j][rr];
      *(half4*)(Lw + row*256 + c*8) = oq;
    }
  }
  #pragma unroll
  for (int s = 0; s < 16; ++s){
    int row = s*4 + kg;
    int cc = (2*lr) ^ ((row & 7)*4);
    half8 hv = *(const half8*)(Lw + row*256 + cc*8);
    *(half8*)&O[(size_t)(m0 + wm*64 + row)*NN + v0 + wv*128 + lr*8] = hv;
  }
}

// ---------------- 1x1 mix via MFMA over Krylov basis (v2) -------------------
// out[o][v] = sum_{kt,c} U[o][kt*64+c] * S_kt[b,c,l,v] per (b,l), v-half 256.
// The c-contraction needs k-contiguous fragments; states are v-contiguous, so
// the inherent transpose is done ONCE, vectorized: in-register 8x8 f16
// transpose (v_perm_b32, 32 perms/64 elems) at staging, LDS holds X^T [v][c]
// with chunk-XOR swizzle slot=(c>>3)^(((v>>3)&1)<<2) -> conflict-free writes
// AND b128 frag reads (replaces 320 ds_read_u16/thread + 4.16M conflicts).
// U fragments load straight from global (40KB, L2-resident); LDS 33KB.
// MFMA order identical to v1 -> bit-identical numerics.
template<int PASS>
__global__ __launch_bounds__(256, 3) void combine_mfma(
    const _Float16* __restrict__ Sh, const _Float16* __restrict__ S2,
    const _Float16* __restrict__ S3, const _Float16* __restrict__ S4,
    const _Float16* __restrict__ Sf,
    const _Float16* __restrict__ Wc,   // U_p [64][320] f16
    const float* __restrict__ bias,    // [64]
    _Float16* __restrict__ tmp){
  __shared__ __align__(16) _Float16 Xt[256*64];   // X^T [v][c], swizzled; 32KB
  __shared__ float Bsh[64];
  int v0 = blockIdx.x * 256;
  int l  = blockIdx.y;
  int b  = blockIdx.z;
  int tid = threadIdx.x;
  int w = tid >> 6, lane = tid & 63;
  int lr = lane & 15, kg = lane >> 4;

  if (tid < 64) Bsh[tid] = bias[tid];

  // staging geometry: thread owns an 8x8 block at (c0, lv0)
  const int c0  = ((tid >> 3) & 7) * 8;          // 8 c-rows
  const int lv0 = (tid & 7) * 8 + w * 64;        // 8 local v-cols
  const int wslot = (c0 >> 3) ^ (((lv0 >> 3) & 1) << 2);
  const int rx = ((lr >> 3) & 1) << 2;           // read-side chunk xor

  const _Float16* Sarr[5] = {Sh, S2, S3, S4, Sf};
  f32x4 acc[4][4] = {};   // [vt][jj]

  for (int kt = 0; kt < 5; ++kt){
    const _Float16* S = Sarr[kt];
    // global loads: rows c0..c0+7 (stride 58*512), cols v0+lv0..+7 (16B)
    unsigned xr[8][4];
    const _Float16* gbase = &S[((size_t)(b*64 + c0)*58 + l)*512 + v0 + lv0];
    #pragma unroll
    for (int r = 0; r < 8; ++r)
      *(uint4*)xr[r] = *(const uint4*)(gbase + (size_t)r*58*512);

    __syncthreads();    // prev kt's frag reads done (kt=0: covers Bsh)

    // 8x8 in-register transpose -> 8 v-rows, then b128 LDS writes
    #pragma unroll
    for (int q = 0; q < 8; ++q){
      const unsigned sel = (q & 1) ? 0x07060302u : 0x05040100u;
      const int d2 = q >> 1;
      uint4 y;
      y.x = __builtin_amdgcn_perm(xr[1][d2], xr[0][d2], sel);
      y.y = __builtin_amdgcn_perm(xr[3][d2], xr[2][d2], sel);
      y.z = __builtin_amdgcn_perm(xr[5][d2], xr[4][d2], sel);
      y.w = __builtin_amdgcn_perm(xr[7][d2], xr[6][d2], sel);
      *(uint4*)((char*)Xt + (lv0 + q)*128 + wslot*16) = y;
    }

    // U fragments for this kt straight from global (L2/L1-hot)
    half8 aW[2][4];
    #pragma unroll
    for (int ks = 0; ks < 2; ++ks)
      #pragma unroll
      for (int jj = 0; jj < 4; ++jj)
        aW[ks][jj] = *(const half8*)&Wc[(size_t)(jj*16 + lr)*320
                                        + kt*64 + ks*32 + kg*8];

    __syncthreads();

    #pragma unroll
    for (int ks = 0; ks < 2; ++ks){
      #pragma unroll
      for (int vt = 0; vt < 4; ++vt){
        half8 bf = *(const half8*)((char*)Xt + (w*64 + vt*16 + lr)*128
                                   + ((ks*4 + kg) ^ rx)*16);
        #pragma unroll
        for (int jj = 0; jj < 4; ++jj)
          acc[vt][jj] = __builtin_amdgcn_mfma_f32_16x16x32_f16(
              aW[ks][jj], bf, acc[vt][jj], 0, 0, 0);
      }
    }
  }

  size_t rowbase = ((size_t)b*58 + l)*64;
  #pragma unroll
  for (int jj = 0; jj < 4; ++jj){
    #pragma unroll
    for (int rr = 0; rr < 4; ++rr){
      int o = jj*16 + kg*4 + rr;
      float bv = Bsh[o];
      size_t obase = (rowbase + o)*512 + v0 + w*64 + lr;
      #pragma unroll
      for (int vt = 0; vt < 4; ++vt){
        float val = acc[vt][jj][rr] + bv;
        size_t addr = obase + vt*16;
        if (PASS == 0) tmp[addr] = (_Float16)val;
        else           tmp[addr] = (_Float16)((float)tmp[addr] + val);
      }
    }
  }
}

// ---------------- untranspose tmp[(b,l)][o][v] -> out[b][o][v][6+l], zero pad ----------------
__global__ __launch_bounds__(256) void untranspose(const _Float16* __restrict__ tmp,
                                                   float* __restrict__ out){
  __shared__ float T[58][65];
  int o = blockIdx.x;          // 64
  int b = blockIdx.y;          // 8
  int v0 = blockIdx.z * 64;    // 8
  int t = threadIdx.x;
  for (int idx = t; idx < 58*64; idx += 256){
    int lr = idx >> 6, vv = idx & 63;
    T[lr][vv] = (float)tmp[((size_t)(b*58 + lr)*64 + o)*NN + v0 + vv];
  }
  __syncthreads();
  #pragma unroll
  for (int i = 0; i < 16; ++i){
    int c = t + i*256;           // 0..4095
    int vv = c >> 6, tt = c & 63;
    float val = (tt < 6) ? 0.f : T[tt - 6][vv];
    out[((size_t)(b*64 + o)*NN + v0 + vv)*TT + tt] = val;
  }
}

// ---------------- launch ----------------
extern "C" void kernel_launch(void* const* d_in, const int* in_sizes, int n_in,
                              void* d_out, int out_size, void* d_ws, size_t ws_size,
                              hipStream_t stream){
  const float* x   = (const float*)d_in[0];
  const float* adj = (const float*)d_in[1];
  const float* w1[4] = {(const float*)d_in[2],  (const float*)d_in[4],
                        (const float*)d_in[6],  (const float*)d_in[8]};
  const float* b1[4] = {(const float*)d_in[3],  (const float*)d_in[5],
                        (const float*)d_in[7],  (const float*)d_in[9]};
  const float* w2[4] = {(const float*)d_in[10], (const float*)d_in[12],
                        (const float*)d_in[14], (const float*)d_in[16]};
  const float* b2[4] = {(const float*)d_in[11], (const float*)d_in[13],
                        (const float*)d_in[15], (const float*)d_in[17]};
  const float* m1w = (const float*)d_in[18];
  const float* m1b = (const float*)d_in[19];
  const float* m2w = (const float*)d_in[20];
  const float* m2b = (const float*)d_in[21];

  // workspace layout (bytes) — total ~185 MB
  char* wsb = (char*)d_ws;
  float* dinv1 = (float*)(wsb);
  float* dinv2 = (float*)(wsb + 2048);
  _Float16* U1  = (_Float16*)(wsb + 4096);             // 40 KB
  _Float16* U2  = (_Float16*)(wsb + 4096 + 40960);     // 40 KB
  _Float16* Mn  = (_Float16*)(wsb + 167936);           // M = An - I
  _Float16* MnT = (_Float16*)(wsb + 167936 + 524288);
  size_t sbytes = SZ * 2;
  char* sbase = wsb + 1216512;
  _Float16* S_h = (_Float16*)(sbase);                  // z0 = h
  _Float16* S2  = (_Float16*)(sbase + sbytes);         // z1
  _Float16* S3  = (_Float16*)(sbase + 2*sbytes);       // z2
  _Float16* S4  = (_Float16*)(sbase + 3*sbytes);       // z3
  _Float16* S5  = (_Float16*)(sbase + 4*sbytes);       // z4
  _Float16* tmp = (_Float16*)(sbase + 5*sbytes);
  _Float16* xTg = S2;   // dead before first gemm writes S2
  _Float16* WfG = (_Float16*)(sbase + 6*sbytes);        // 114688 B
  float* biasFG = (float*)(sbase + 6*sbytes + 114688);  // 512 B
  _Float16* M2  = (_Float16*)(sbase + 6*sbytes + 131072);           // 512 KB
  _Float16* MT2 = (_Float16*)(sbase + 6*sbytes + 131072 + 524288);  // 512 KB
  float* out = (float*)d_out;

  prep_adj<<<NN, 64, 0, stream>>>(adj, dinv1, dinv2);
  build_norm<<<NN, 256, 0, stream>>>(adj, dinv1, dinv2, Mn, MnT);
  // M2 = Mn^2 row-major = gemm(A=MnT,B=Mn); MT2 = MnT^2 row-major = gemm(A=Mn,B=MnT)
  gemm_z2<<<8, 512, 0, stream>>>(2, MnT, Mn, M2, Mn, MnT, MT2);
  u_prep<<<80, 256, 0, stream>>>(m1w, m2w, U1, U2);
  wfg_prep<<<128, 448, 0, stream>>>(
      w1[0],w1[1],w1[2],w1[3], w2[0],w2[1],w2[2],w2[3],
      b1[0],b1[1],b1[2],b1[3], b2[0],b2[1],b2[2],b2[3], WfG, biasFG);
  xt_prep<<<dim3(NN, BB), 256, 0, stream>>>(x, xTg);
  inception_mfma<<<dim3(16, 9, 8), 256, 0, stream>>>(xTg, WfG, biasFG, S_h);

  dim3 gc(2, LL, BB);
  for (int pass = 0; pass < 2; ++pass){
    const _Float16* Mp  = pass ? MnT : Mn;
    const _Float16* Mp2 = pass ? MT2 : M2;
    // z1 = Mp·h, z2 = Mp²·h   (independent)
    gemm_z2<<<464, 512, 0, stream>>>(116, Mp, S_h, S2, Mp2, S_h, S3);
    // z3 = Mp²·z1, z4 = Mp²·z2 (independent)
    gemm_z2<<<464, 512, 0, stream>>>(116, Mp2, S2, S4, Mp2, S3, S5);
    if (pass == 0)
      combine_mfma<0><<<gc, 256, 0, stream>>>(S_h, S2, S3, S4, S5, U1, m1b, tmp);
    else
      combine_mfma<1><<<gc, 256, 0, stream>>>(S_h, S2, S3, S4, S5, U2, m2b, tmp);
  }
  untranspose<<<dim3(64, 8, 8), 256, 0, stream>>>(tmp, out);
}

// Round 4
// 460.696 us; speedup vs baseline: 1.2565x; 1.0238x over previous
//
#include <hip/hip_runtime.h>
#include <math.h>

#define NN 512
#define BB 8
#define CC 64
#define TT 64
#define LL 58
#define CL (CC*LL)        // 3712
#define BCL (BB*CC*LL)    // 29696
#define SZ ((size_t)NN*BCL)   // 15,204,352 elements per state

typedef _Float16 half8 __attribute__((ext_vector_type(8)));
typedef _Float16 half4 __attribute__((ext_vector_type(4)));
typedef float f32x4 __attribute__((ext_vector_type(4)));

// ---------------- adjacency normalization ----------------
__global__ __launch_bounds__(64) void prep_adj(const float* __restrict__ adj,
                                               float* __restrict__ dinv1,
                                               float* __restrict__ dinv2){
  int v = blockIdx.x;
  int lane = threadIdx.x;
  float rs = 0.f, cs = 0.f;
  for (int w = lane; w < NN; w += 64){
    rs += adj[v*NN + w];
    cs += adj[w*NN + v];
  }
  for (int off = 32; off > 0; off >>= 1){
    rs += __shfl_down(rs, off);
    cs += __shfl_down(cs, off);
  }
  if (lane == 0){
    dinv1[v] = 1.f / sqrtf(rs + 1.f);
    dinv2[v] = 1.f / sqrtf(cs + 1.f);
  }
}

// emits M = D^-1/2(A+I)D^-1/2 - I  (f(y) = M·y since 0.5*ALPHA = 1, DT=1)
__global__ __launch_bounds__(256) void build_norm(const float* __restrict__ adj,
                                                  const float* __restrict__ dinv1,
                                                  const float* __restrict__ dinv2,
                                                  _Float16* __restrict__ An,
                                                  _Float16* __restrict__ AnT){
  int v = blockIdx.x;
  float d1v = dinv1[v], d2v = dinv2[v];
  for (int w = threadIdx.x; w < NN; w += 256){
    float diag = (v == w) ? 1.f : 0.f;
    An[v*NN + w]  = (_Float16)(d1v * (adj[v*NN + w] + diag) * dinv1[w] - diag);
    AnT[v*NN + w] = (_Float16)(d2v * (adj[w*NN + v] + diag) * dinv2[w] - diag);
  }
}

// ---------------- U prep: fold RK/concat coefficients into combine weights ----
__global__ __launch_bounds__(256) void u_prep(const float* __restrict__ W1,
                                              const float* __restrict__ W2,
                                              _Float16* __restrict__ U1,
                                              _Float16* __restrict__ U2){
  const float coef[5][5] = {
    {1.f, 1.f, 1.f, 1.f, 1.f},
    {0.f, 1.f/3.f, 2.f/3.f, 1.f, 1.f},
    {0.f, 0.f, 1.f/3.f, 1.f/3.f, 0.5f},
    {0.f, 0.f, 0.f, 1.f/3.f, 1.f/6.f},
    {0.f, 0.f, 0.f, 0.f, 1.f/24.f}};
  int idx = blockIdx.x*256 + threadIdx.x;   // grid 80 -> 20480
  int o = idx / 320, rem = idx - o*320;
  int d = rem >> 6, c = rem & 63;
  float a1 = 0.f, a2 = 0.f;
  #pragma unroll
  for (int s = 0; s < 5; ++s){
    float cf = coef[d][s];
    a1 += cf * W1[o*320 + s*64 + c];
    a2 += cf * W2[o*320 + s*64 + c];
  }
  U1[idx] = (_Float16)a1;
  U2[idx] = (_Float16)a2;
}

// ---------------- inception weight prep ----------------
__global__ __launch_bounds__(448) void wfg_prep(
    const float* __restrict__ w10, const float* __restrict__ w11,
    const float* __restrict__ w12, const float* __restrict__ w13,
    const float* __restrict__ w20, const float* __restrict__ w21,
    const float* __restrict__ w22, const float* __restrict__ w23,
    const float* __restrict__ b10, const float* __restrict__ b11,
    const float* __restrict__ b12, const float* __restrict__ b13,
    const float* __restrict__ b20, const float* __restrict__ b21,
    const float* __restrict__ b22, const float* __restrict__ b23,
    _Float16* __restrict__ WfG, float* __restrict__ biasFG){
  int r = blockIdx.x;         // 0..127
  int t = threadIdx.x;        // 0..447
  int qp = t >> 6, ic = t & 63;
  int gate = r >> 6;
  int j = (r >> 4) & 3;
  int oc = r & 15;
  const int kjs[4] = {2, 3, 6, 7};
  int kj = kjs[j];
  const float* wsel = gate ? ((j==0)?w20:(j==1)?w21:(j==2)?w22:w23)
                           : ((j==0)?w10:(j==1)?w11:(j==2)?w12:w13);
  int off = 7 - kj;
  float val = (qp >= off) ? wsel[(oc*64 + ic)*kj + (qp - off)] : 0.f;
  WfG[(size_t)r*448 + t] = (_Float16)val;
  if (t == 0){
    const float* bsel = gate ? ((j==0)?b20:(j==1)?b21:(j==2)?b22:b23)
                             : ((j==0)?b10:(j==1)?b11:(j==2)?b12:b13);
    biasFG[r] = bsel[oc];
  }
}

// ---------------- x transpose: x[b][ic][n][t] f32 -> xTg[b][t][n][ic] f16 ----------------
__global__ __launch_bounds__(256) void xt_prep(const float* __restrict__ x,
                                               _Float16* __restrict__ xTg){
  __shared__ float T[64][65];
  int n = blockIdx.x;   // 512
  int b = blockIdx.y;   // 8
  int tid = threadIdx.x;
  #pragma unroll
  for (int r = 0; r < 4; ++r){
    int f = tid + r*256;       // 0..1023
    int ic = f >> 4, t4 = f & 15;
    float4 v = *(const float4*)&x[(((size_t)(b*64 + ic))*512 + n)*64 + t4*4];
    T[ic][t4*4+0] = v.x; T[ic][t4*4+1] = v.y;
    T[ic][t4*4+2] = v.z; T[ic][t4*4+3] = v.w;
  }
  __syncthreads();
  #pragma unroll
  for (int r = 0; r < 2; ++r){
    int f = tid + r*256;       // 0..511
    int t = f >> 3, ch = f & 7;
    half8 hv;
    #pragma unroll
    for (int q2 = 0; q2 < 8; ++q2) hv[q2] = (_Float16)T[ch*8 + q2][t];
    *(half8*)&xTg[(((size_t)(b*64 + t))*512 + n)*64 + ch*8] = hv;
  }
}

// ---------------- inception via MFMA ----------------
__global__ __launch_bounds__(256, 3) void inception_mfma(
    const _Float16* __restrict__ xTg,   // [b][t][n][ic]
    const _Float16* __restrict__ WfG,   // [128][448]
    const float* __restrict__ biasFG,   // [128]
    _Float16* __restrict__ S_h){
  __shared__ _Float16 X[13*32*64];      // indexed in 8-half chunks
  int nt = blockIdx.x;   // 0..15
  int lt = blockIdx.y;   // 0..8
  int b  = blockIdx.z;   // 0..7
  int n0 = nt*32, l0 = lt*7;
  int tid = threadIdx.x;

  int sch = tid & 7, sn = (tid >> 3) & 31;
  #pragma unroll
  for (int r = 0; r < 13; ++r){
    int t = l0 + r;
    half8 v = {};
    if (t < 64)
      v = *(const half8*)&xTg[(((size_t)(b*64 + t))*512 + n0 + sn)*64 + sch*8];
    *(half8*)&X[(size_t)(r*256 + sn*8 + (sch ^ (sn & 7)))*8] = v;
  }

  int w = tid >> 6, lane = tid & 63;
  int m = lane & 15, kg = lane >> 4;

  half8 wF[14], wG[14];
  const _Float16* wb = WfG + (size_t)(w*16 + m)*448 + kg*8;
  #pragma unroll
  for (int s = 0; s < 14; ++s){
    wF[s] = *(const half8*)(wb + s*32);
    wG[s] = *(const half8*)(wb + (size_t)64*448 + s*32);
  }
  f32x4 bF = *(const f32x4*)&biasFG[w*16 + kg*4];
  f32x4 bG = *(const f32x4*)&biasFG[64 + w*16 + kg*4];

  __syncthreads();

  for (int ll = 0; ll < 7; ++ll){
    f32x4 aF0 = {}, aF1 = {}, aG0 = {}, aG1 = {};
    #pragma unroll
    for (int s = 0; s < 14; ++s){
      int t = ll + (s >> 1);
      int c0 = (s & 1)*4 + kg;
      half8 b0 = *(half8*)&X[(size_t)(t*256 + m*8        + (c0 ^ (m & 7)))*8];
      half8 b1 = *(half8*)&X[(size_t)(t*256 + (16+m)*8   + (c0 ^ (m & 7)))*8];
      aF0 = __builtin_amdgcn_mfma_f32_16x16x32_f16(wF[s], b0, aF0, 0, 0, 0);
      aG0 = __builtin_amdgcn_mfma_f32_16x16x32_f16(wG[s], b0, aG0, 0, 0, 0);
      aF1 = __builtin_amdgcn_mfma_f32_16x16x32_f16(wF[s], b1, aF1, 0, 0, 0);
      aG1 = __builtin_amdgcn_mfma_f32_16x16x32_f16(wG[s], b1, aG1, 0, 0, 0);
    }
    int l = l0 + ll;
    if (l < LL){
      #pragma unroll
      for (int rr = 0; rr < 4; ++rr){
        int c = w*16 + kg*4 + rr;
        float F0 = aF0[rr] + bF[rr];
        float G0 = aG0[rr] + bG[rr];
        float F1 = aF1[rr] + bF[rr];
        float G1 = aG1[rr] + bG[rr];
        float h0 = (2.f*__builtin_amdgcn_rcpf(1.f + __expf(-2.f*F0)) - 1.f)
                 * __builtin_amdgcn_rcpf(1.f + __expf(-G0));
        float h1 = (2.f*__builtin_amdgcn_rcpf(1.f + __expf(-2.f*F1)) - 1.f)
                 * __builtin_amdgcn_rcpf(1.f + __expf(-G1));
        size_t base = ((size_t)(b*64 + c)*LL + l)*NN + n0;
        S_h[base + m]      = (_Float16)h0;
        S_h[base + 16 + m] = (_Float16)h1;
      }
    }
  }
}

// ---------------- dual Krylov GEMM v4: 128x256 tile, 4 waves, BK=32 ---------
// O[m][v] = sum_k B[m][k] * A[v][k].  A = 512x512 M matrix (L2-hot), B = state.
// 2 blocks/CU (64KB LDS, VGPR<=~230 at 2 waves/SIMD) -> cross-block overlap
// fills the barrier stalls that capped v3 at MfmaUtil 25%.
// LDS: dbuf x (A 256x32 + B 128x32 halfs) = 48KB; rows 64B (4x16B chunks).
// ROTATION swizzle (round-0-proven conflict-free): LDS slot s of row r holds
// global chunk (s - (r>>1))&3; applied on the GLOBAL source (linear LDS dest,
// as global_load_lds requires): lane l sources chunk ((l&3)-((l>>3)&3))&3.
// Read side: slot=(kg+(lr>>1))&3 -> 8 distinct bank-quads per 8-lane batch.
// Counted vmcnt(6) (6 gll16/tile), never 0 until the tail; 2 barriers/K-tile.
// K order ascending -> bit-identical numerics to v3.
__device__ __forceinline__ void gll16(const _Float16* g, _Float16* l){
  __builtin_amdgcn_global_load_lds(
      (const __attribute__((address_space(1))) unsigned int*)g,
      (__attribute__((address_space(3))) unsigned int*)l, 16, 0, 0);
}
#define BAR() asm volatile("s_barrier" ::: "memory")

__global__ __launch_bounds__(256, 2) void gemm_z2(
    int nx,
    const _Float16* __restrict__ A0, const _Float16* __restrict__ B0,
    _Float16* __restrict__ O0,
    const _Float16* __restrict__ A1, const _Float16* __restrict__ B1,
    _Float16* __restrict__ O1){
  __shared__ _Float16 L[32768];   // 64 KB: [0,48K) staging dbuf; 64KB epilogue

  // bijective XCD-chunked remap (gridDim.x % 8 == 0); y-pairs (shared B rows)
  // adjacent within an XCD chunk -> second B read is an L2 hit.
  int bid = blockIdx.x;
  int q8 = gridDim.x >> 3;
  int virt = (bid & 7)*q8 + (bid >> 3);
  int y = virt & 1;
  int pair = virt >> 1;
  int x = pair % nx;
  int z = pair / nx;

  const _Float16* __restrict__ A = z ? A1 : A0;
  const _Float16* __restrict__ B = z ? B1 : B0;
  _Float16* __restrict__ O = z ? O1 : O0;

  const int m0 = x * 128;
  const int v0 = y * 256;
  const int tid = threadIdx.x;
  const int ww = tid >> 6;          // 0..3
  const int lane = tid & 63;
  const int lr = lane & 15;
  const int kg = lane >> 4;
  const int wvq = ww & 1;           // v half   (128 rows, i 0..7)
  const int wmq = ww >> 1;          // m half   (64 rows,  j 0..3)

  // staging: per gll16, 64 lanes fill 16 rows x 4 chunks(16B) linear.
  // lane l -> row l>>2, LDS slot l&3; global chunk = ((l&3)-((l>>3)&3))&3.
  const int srow = lane >> 2;
  const int gch  = ((lane & 3) - ((lane >> 3) & 3)) & 3;
  const _Float16* gAb = A + (size_t)(v0 + ww*64 + srow)*NN + gch*8;
  const _Float16* gBb = B + (size_t)(m0 + ww*32 + srow)*NN + gch*8;

  // LDS bytes: buf*24576 + [A: row*64 | B: 16384 + row*64] + chunk*16
  #define STAGE(buf, kt)                                                    \
    { char* lA_ = (char*)L + (buf)*24576 + ww*4096;                         \
      char* lB_ = (char*)L + (buf)*24576 + 16384 + ww*2048;                 \
      const _Float16* gA_ = gAb + (kt)*32;                                  \
      const _Float16* gB_ = gBb + (kt)*32;                                  \
      _Pragma("unroll")                                                     \
      for (int s_ = 0; s_ < 4; ++s_)                                        \
        gll16(gA_ + (size_t)s_*16*NN, (_Float16*)(lA_ + s_*1024));          \
      _Pragma("unroll")                                                     \
      for (int s_ = 0; s_ < 2; ++s_)                                        \
        gll16(gB_ + (size_t)s_*16*NN, (_Float16*)(lB_ + s_*1024)); }

  // read-side rotation slot (uniform across i/j: base rows are mult. of 8)
  const int slot = (kg + (lr >> 1)) & 3;
  const int aOff = (wvq*128 + lr)*64 + slot*16;          // + i*1024
  const int bOff = 16384 + (wmq*64 + lr)*64 + slot*16;   // + j*1024

  half8 af[8], bf[4];
  f32x4 acc[8][4] = {};

  // prologue: tiles 0,1 in flight (12 loads); wait tile 0 -> vmcnt(6)
  STAGE(0, 0)
  STAGE(1, 1)
  asm volatile("s_waitcnt vmcnt(6)" ::: "memory");
  BAR();

  #pragma unroll
  for (int kt = 0; kt < 16; ++kt){
    const int buf = kt & 1;
    char* lb = (char*)L + buf*24576;
    #pragma unroll
    for (int i = 0; i < 8; ++i) af[i] = *(const half8*)(lb + aOff + i*1024);
    #pragma unroll
    for (int j = 0; j < 4; ++j) bf[j] = *(const half8*)(lb + bOff + j*1024);
    asm volatile("s_waitcnt lgkmcnt(0)" ::: "memory");
    BAR();                                   // all waves done reading buf
    if (kt + 2 < 16) STAGE(buf, kt + 2)      // safe to overwrite with kt+2

    __builtin_amdgcn_s_setprio(1);
    #pragma unroll
    for (int i = 0; i < 8; ++i)
      #pragma unroll
      for (int j = 0; j < 4; ++j)
        acc[i][j] = __builtin_amdgcn_mfma_f32_16x16x32_f16(af[i], bf[j], acc[i][j], 0, 0, 0);
    __builtin_amdgcn_s_setprio(0);

    if (kt < 14){
      asm volatile("s_waitcnt vmcnt(6)" ::: "memory");   // kt+1 landed, kt+2 in flight
      BAR();
    } else if (kt == 14){
      asm volatile("s_waitcnt vmcnt(0)" ::: "memory");   // tail drain
      BAR();
    }
  }
  #undef STAGE

  // ---- epilogue: per-wave 16KB LDS transpose -> coalesced 256B row stores.
  // local tile [m'=64][v'=128] halfs, row=256B; 8B-chunk swizzle ^(row&7)*4.
  // (after kt=15's first BAR, no wave reads staging LDS again -> safe reuse)
  char* Lw = (char*)L + ww*16384;
  #pragma unroll
  for (int j = 0; j < 4; ++j){
    int row = j*16 + lr;
    #pragma unroll
    for (int i = 0; i < 8; ++i){
      int c = (i*4 + kg) ^ ((lr & 7)*4);
      half4 oq;
      #pragma unroll
      for (int rr = 0; rr < 4; ++rr) oq[rr] = (_Float16)acc[i][j][rr];
      *(half4*)(Lw + row*256 + c*8) = oq;
    }
  }
  #pragma unroll
  for (int s = 0; s < 16; ++s){
    int row = s*4 + kg;
    int cc = (2*lr) ^ ((row & 7)*4);
    half8 hv = *(const half8*)(Lw + row*256 + cc*8);
    *(half8*)&O[(size_t)(m0 + wmq*64 + row)*NN + v0 + wvq*128 + lr*8] = hv;
  }
}

// ---------------- 1x1 mix via MFMA over Krylov basis (v2) -------------------
// out[o][v] = sum_{kt,c} U[o][kt*64+c] * S_kt[b,c,l,v] per (b,l), v-half 256.
// In-register 8x8 f16 transpose (v_perm_b32) at staging, LDS holds X^T [v][c]
// with chunk-XOR swizzle; U fragments straight from global (L2-resident).
template<int PASS>
__global__ __launch_bounds__(256, 3) void combine_mfma(
    const _Float16* __restrict__ Sh, const _Float16* __restrict__ S2,
    const _Float16* __restrict__ S3, const _Float16* __restrict__ S4,
    const _Float16* __restrict__ Sf,
    const _Float16* __restrict__ Wc,   // U_p [64][320] f16
    const float* __restrict__ bias,    // [64]
    _Float16* __restrict__ tmp){
  __shared__ __align__(16) _Float16 Xt[256*64];   // X^T [v][c], swizzled; 32KB
  __shared__ float Bsh[64];
  int v0 = blockIdx.x * 256;
  int l  = blockIdx.y;
  int b  = blockIdx.z;
  int tid = threadIdx.x;
  int w = tid >> 6, lane = tid & 63;
  int lr = lane & 15, kg = lane >> 4;

  if (tid < 64) Bsh[tid] = bias[tid];

  // staging geometry: thread owns an 8x8 block at (c0, lv0)
  const int c0  = ((tid >> 3) & 7) * 8;          // 8 c-rows
  const int lv0 = (tid & 7) * 8 + w * 64;        // 8 local v-cols
  const int wslot = (c0 >> 3) ^ (((lv0 >> 3) & 1) << 2);
  const int rx = ((lr >> 3) & 1) << 2;           // read-side chunk xor

  const _Float16* Sarr[5] = {Sh, S2, S3, S4, Sf};
  f32x4 acc[4][4] = {};   // [vt][jj]

  for (int kt = 0; kt < 5; ++kt){
    const _Float16* S = Sarr[kt];
    // global loads: rows c0..c0+7 (stride 58*512), cols v0+lv0..+7 (16B)
    unsigned xr[8][4];
    const _Float16* gbase = &S[((size_t)(b*64 + c0)*58 + l)*512 + v0 + lv0];
    #pragma unroll
    for (int r = 0; r < 8; ++r)
      *(uint4*)xr[r] = *(const uint4*)(gbase + (size_t)r*58*512);

    __syncthreads();    // prev kt's frag reads done (kt=0: covers Bsh)

    // 8x8 in-register transpose -> 8 v-rows, then b128 LDS writes
    #pragma unroll
    for (int q = 0; q < 8; ++q){
      const unsigned sel = (q & 1) ? 0x07060302u : 0x05040100u;
      const int d2 = q >> 1;
      uint4 y;
      y.x = __builtin_amdgcn_perm(xr[1][d2], xr[0][d2], sel);
      y.y = __builtin_amdgcn_perm(xr[3][d2], xr[2][d2], sel);
      y.z = __builtin_amdgcn_perm(xr[5][d2], xr[4][d2], sel);
      y.w = __builtin_amdgcn_perm(xr[7][d2], xr[6][d2], sel);
      *(uint4*)((char*)Xt + (lv0 + q)*128 + wslot*16) = y;
    }

    // U fragments for this kt straight from global (L2/L1-hot)
    half8 aW[2][4];
    #pragma unroll
    for (int ks = 0; ks < 2; ++ks)
      #pragma unroll
      for (int jj = 0; jj < 4; ++jj)
        aW[ks][jj] = *(const half8*)&Wc[(size_t)(jj*16 + lr)*320
                                        + kt*64 + ks*32 + kg*8];

    __syncthreads();

    #pragma unroll
    for (int ks = 0; ks < 2; ++ks){
      #pragma unroll
      for (int vt = 0; vt < 4; ++vt){
        half8 bf = *(const half8*)((char*)Xt + (w*64 + vt*16 + lr)*128
                                   + ((ks*4 + kg) ^ rx)*16);
        #pragma unroll
        for (int jj = 0; jj < 4; ++jj)
          acc[vt][jj] = __builtin_amdgcn_mfma_f32_16x16x32_f16(
              aW[ks][jj], bf, acc[vt][jj], 0, 0, 0);
      }
    }
  }

  size_t rowbase = ((size_t)b*58 + l)*64;
  #pragma unroll
  for (int jj = 0; jj < 4; ++jj){
    #pragma unroll
    for (int rr = 0; rr < 4; ++rr){
      int o = jj*16 + kg*4 + rr;
      float bv = Bsh[o];
      size_t obase = (rowbase + o)*512 + v0 + w*64 + lr;
      #pragma unroll
      for (int vt = 0; vt < 4; ++vt){
        float val = acc[vt][jj][rr] + bv;
        size_t addr = obase + vt*16;
        if (PASS == 0) tmp[addr] = (_Float16)val;
        else           tmp[addr] = (_Float16)((float)tmp[addr] + val);
      }
    }
  }
}

// ---------------- untranspose tmp[(b,l)][o][v] -> out[b][o][v][6+l], zero pad ----------------
__global__ __launch_bounds__(256) void untranspose(const _Float16* __restrict__ tmp,
                                                   float* __restrict__ out){
  __shared__ float T[58][65];
  int o = blockIdx.x;          // 64
  int b = blockIdx.y;          // 8
  int v0 = blockIdx.z * 64;    // 8
  int t = threadIdx.x;
  for (int idx = t; idx < 58*64; idx += 256){
    int lr = idx >> 6, vv = idx & 63;
    T[lr][vv] = (float)tmp[((size_t)(b*58 + lr)*64 + o)*NN + v0 + vv];
  }
  __syncthreads();
  #pragma unroll
  for (int i = 0; i < 16; ++i){
    int c = t + i*256;           // 0..4095
    int vv = c >> 6, tt = c & 63;
    float val = (tt < 6) ? 0.f : T[tt - 6][vv];
    out[((size_t)(b*64 + o)*NN + v0 + vv)*TT + tt] = val;
  }
}

// ---------------- launch ----------------
extern "C" void kernel_launch(void* const* d_in, const int* in_sizes, int n_in,
                              void* d_out, int out_size, void* d_ws, size_t ws_size,
                              hipStream_t stream){
  const float* x   = (const float*)d_in[0];
  const float* adj = (const float*)d_in[1];
  const float* w1[4] = {(const float*)d_in[2],  (const float*)d_in[4],
                        (const float*)d_in[6],  (const float*)d_in[8]};
  const float* b1[4] = {(const float*)d_in[3],  (const float*)d_in[5],
                        (const float*)d_in[7],  (const float*)d_in[9]};
  const float* w2[4] = {(const float*)d_in[10], (const float*)d_in[12],
                        (const float*)d_in[14], (const float*)d_in[16]};
  const float* b2[4] = {(const float*)d_in[11], (const float*)d_in[13],
                        (const float*)d_in[15], (const float*)d_in[17]};
  const float* m1w = (const float*)d_in[18];
  const float* m1b = (const float*)d_in[19];
  const float* m2w = (const float*)d_in[20];
  const float* m2b = (const float*)d_in[21];

  // workspace layout (bytes) — total ~185 MB
  char* wsb = (char*)d_ws;
  float* dinv1 = (float*)(wsb);
  float* dinv2 = (float*)(wsb + 2048);
  _Float16* U1  = (_Float16*)(wsb + 4096);             // 40 KB
  _Float16* U2  = (_Float16*)(wsb + 4096 + 40960);     // 40 KB
  _Float16* Mn  = (_Float16*)(wsb + 167936);           // M = An - I
  _Float16* MnT = (_Float16*)(wsb + 167936 + 524288);
  size_t sbytes = SZ * 2;
  char* sbase = wsb + 1216512;
  _Float16* S_h = (_Float16*)(sbase);                  // z0 = h
  _Float16* S2  = (_Float16*)(sbase + sbytes);         // z1
  _Float16* S3  = (_Float16*)(sbase + 2*sbytes);       // z2
  _Float16* S4  = (_Float16*)(sbase + 3*sbytes);       // z3
  _Float16* S5  = (_Float16*)(sbase + 4*sbytes);       // z4
  _Float16* tmp = (_Float16*)(sbase + 5*sbytes);
  _Float16* xTg = S2;   // dead before first gemm writes S2
  _Float16* WfG = (_Float16*)(sbase + 6*sbytes);        // 114688 B
  float* biasFG = (float*)(sbase + 6*sbytes + 114688);  // 512 B
  _Float16* M2  = (_Float16*)(sbase + 6*sbytes + 131072);           // 512 KB
  _Float16* MT2 = (_Float16*)(sbase + 6*sbytes + 131072 + 524288);  // 512 KB
  float* out = (float*)d_out;

  prep_adj<<<NN, 64, 0, stream>>>(adj, dinv1, dinv2);
  build_norm<<<NN, 256, 0, stream>>>(adj, dinv1, dinv2, Mn, MnT);
  // M2 = Mn^2 row-major = gemm(A=MnT,B=Mn); MT2 = MnT^2 row-major = gemm(A=Mn,B=MnT)
  gemm_z2<<<16, 256, 0, stream>>>(4, MnT, Mn, M2, Mn, MnT, MT2);
  u_prep<<<80, 256, 0, stream>>>(m1w, m2w, U1, U2);
  wfg_prep<<<128, 448, 0, stream>>>(
      w1[0],w1[1],w1[2],w1[3], w2[0],w2[1],w2[2],w2[3],
      b1[0],b1[1],b1[2],b1[3], b2[0],b2[1],b2[2],b2[3], WfG, biasFG);
  xt_prep<<<dim3(NN, BB), 256, 0, stream>>>(x, xTg);
  inception_mfma<<<dim3(16, 9, 8), 256, 0, stream>>>(xTg, WfG, biasFG, S_h);

  dim3 gc(2, LL, BB);
  for (int pass = 0; pass < 2; ++pass){
    const _Float16* Mp  = pass ? MnT : Mn;
    const _Float16* Mp2 = pass ? MT2 : M2;
    // z1 = Mp·h, z2 = Mp²·h   (independent)
    gemm_z2<<<928, 256, 0, stream>>>(232, Mp, S_h, S2, Mp2, S_h, S3);
    // z3 = Mp²·z1, z4 = Mp²·z2 (independent)
    gemm_z2<<<928, 256, 0, stream>>>(232, Mp2, S2, S4, Mp2, S3, S5);
    if (pass == 0)
      combine_mfma<0><<<gc, 256, 0, stream>>>(S_h, S2, S3, S4, S5, U1, m1b, tmp);
    else
      combine_mfma<1><<<gc, 256, 0, stream>>>(S_h, S2, S3, S4, S5, U2, m2b, tmp);
  }
  untranspose<<<dim3(64, 8, 8), 256, 0, stream>>>(tmp, out);
}